// Round 2
// baseline (1500.627 us; speedup 1.0000x reference)
//
#include <hip/hip_runtime.h>
#include <hip/hip_bf16.h>
#include <cstdint>

#define N_NODES 100000
#define N_EDGES 800000
#define N_GRAPHS 64

__device__ __forceinline__ float leakyf(float x){ return x >= 0.0f ? x : 0.2f*x; }
__device__ __forceinline__ float reluf(float x){ return x > 0.0f ? x : 0.0f; }

// ---------------- adjacency build (linked lists per dst) ----------------
__global__ void init_head_kernel(int* __restrict__ head, int n){
  int v = blockIdx.x*256 + threadIdx.x;
  if (v < n) head[v] = -1;
}

__global__ void build_list_kernel(const int* __restrict__ dst, int* __restrict__ head,
                                  int* __restrict__ nxt, int E){
  int e = blockIdx.x*256 + threadIdx.x;
  if (e < E) nxt[e] = atomicExch(&head[dst[e]], e);
}

// ---------------- Wa = W @ a (tiny) ----------------
__global__ void wa_kernel(const float* __restrict__ W, const float* __restrict__ a_src,
                          const float* __restrict__ a_dst, float* __restrict__ wa_s,
                          float* __restrict__ wa_d, int K, int Do){
  int k = blockIdx.x*blockDim.x + threadIdx.x;
  if (k >= K) return;
  float ss = 0.f, dd = 0.f;
  const float* wr = W + (size_t)k*Do;
  for (int o = 0; o < Do; ++o){ float w = wr[o]; ss += w*a_src[o]; dd += w*a_dst[o]; }
  wa_s[k] = ss; wa_d[k] = dd;
}

// ---------------- per-node scores: s[v]=in[v]·wa_s, d[v]=in[v]·wa_d ----------------
__global__ __launch_bounds__(256) void sd_kernel(const float* __restrict__ in,
    const float* __restrict__ wa_s, const float* __restrict__ wa_d,
    float* __restrict__ s, float* __restrict__ d, int n, int K){
  int wid = threadIdx.x >> 6, lane = threadIdx.x & 63;
  int v = (blockIdx.x << 2) + wid;
  if (v >= n) return;
  float ss = 0.f, dd = 0.f;
  const float* row = in + (size_t)v*K;
  for (int k = lane; k < K; k += 64){ float x = row[k]; ss += x*wa_s[k]; dd += x*wa_d[k]; }
  for (int off = 32; off; off >>= 1){ ss += __shfl_down(ss, off); dd += __shfl_down(dd, off); }
  if (lane == 0){ s[v] = ss; d[v] = dd; }
}

// ---------------- generic f32 GEMM: C = A[MxK] @ W[KxN] (+bias)(+relu) ----------------
__global__ __launch_bounds__(256) void gemm_kernel(
    const float* __restrict__ A, const float* __restrict__ W,
    const float* __restrict__ bias, float* __restrict__ C,
    int M, int K, int N, int act){
  __shared__ float As[16][68];   // [k][m], padded (68*4B % 16B == 0 keeps float4 alignment)
  __shared__ float Ws[16][64];   // [k][n]
  const int t  = threadIdx.x;
  const int tn = t & 15, tm = t >> 4;
  const int row0 = blockIdx.x * 64;
  const int col0 = blockIdx.y * 64;
  float acc[4][4] = {};
  for (int k0 = 0; k0 < K; k0 += 16){
    // stage A (scalar, guarded)
    #pragma unroll
    for (int i = 0; i < 4; ++i){
      int idx = t + i*256;       // 0..1023
      int m = idx >> 4, k = idx & 15;
      int r = row0 + m, kk = k0 + k;
      float val = 0.f;
      if (r < M && kk < K) val = A[(size_t)r*K + kk];
      As[k][m] = val;
    }
    // stage W (float4, N is always a multiple of 4 here)
    {
      int k = t >> 4, n4 = (t & 15) * 4;
      int kk = k0 + k, c = col0 + n4;
      float4 wv = make_float4(0.f,0.f,0.f,0.f);
      if (kk < K && c + 3 < N) wv = *(const float4*)&W[(size_t)kk*N + c];
      *(float4*)&Ws[k][n4] = wv;
    }
    __syncthreads();
    #pragma unroll
    for (int kk = 0; kk < 16; ++kk){
      const float4 a = *(const float4*)&As[kk][tm*4];
      const float4 w = *(const float4*)&Ws[kk][tn*4];
      acc[0][0] += a.x*w.x; acc[0][1] += a.x*w.y; acc[0][2] += a.x*w.z; acc[0][3] += a.x*w.w;
      acc[1][0] += a.y*w.x; acc[1][1] += a.y*w.y; acc[1][2] += a.y*w.z; acc[1][3] += a.y*w.w;
      acc[2][0] += a.z*w.x; acc[2][1] += a.z*w.y; acc[2][2] += a.z*w.z; acc[2][3] += a.z*w.w;
      acc[3][0] += a.w*w.x; acc[3][1] += a.w*w.y; acc[3][2] += a.w*w.z; acc[3][3] += a.w*w.w;
    }
    __syncthreads();
  }
  const int c = col0 + tn*4;
  if (c >= N) return;
  #pragma unroll
  for (int i = 0; i < 4; ++i){
    int r = row0 + tm*4 + i;
    if (r >= M) continue;
    float4 o;
    float* op = &o.x;
    #pragma unroll
    for (int j = 0; j < 4; ++j){
      float val = acc[i][j];
      if (bias) val += bias[c + j];
      if (act) val = reluf(val);
      op[j] = val;
    }
    *(float4*)&C[(size_t)r*N + c] = o;
  }
}

// ---------------- edge-softmax aggregation: out[v] = relu(sum alpha*h[src] + b) ----------------
template<int NC>   // NC = Do/64 (floats per lane)
__global__ __launch_bounds__(256) void agg_kernel(const float* __restrict__ h,
    const float* __restrict__ s, const float* __restrict__ dsc,
    const int* __restrict__ head, const int* __restrict__ nxt, const int* __restrict__ esrc,
    const float* __restrict__ bias, float* __restrict__ out, int n){
  const int Do = NC*64;
  int wid = threadIdx.x >> 6, lane = threadIdx.x & 63;
  int v = (blockIdx.x << 2) + wid;
  if (v >= n) return;
  const float dv = dsc[v];
  const float e0 = leakyf(s[v] + dv);           // self-loop score
  float m = e0, den = 1.0f;                     // online max / denominator
  const int hd = head[v];
  for (int e = hd; e >= 0; e = nxt[e]){
    float ev = leakyf(s[esrc[e]] + dv);
    if (ev > m){ den = den*__expf(m - ev) + 1.0f; m = ev; }
    else den += __expf(ev - m);
  }
  const float inv = 1.0f / (den + 1e-16f);
  float acc[NC];
  {
    const float w0 = __expf(e0 - m) * inv;
    const float* hp = h + (size_t)v*Do + lane*NC;
    #pragma unroll
    for (int j = 0; j < NC; ++j) acc[j] = w0 * hp[j];
  }
  for (int e = hd; e >= 0; e = nxt[e]){
    int src = esrc[e];
    float w = __expf(leakyf(s[src] + dv) - m) * inv;
    const float* hp = h + (size_t)src*Do + lane*NC;
    #pragma unroll
    for (int j = 0; j < NC; ++j) acc[j] += w * hp[j];
  }
  float* op = out + (size_t)v*Do + lane*NC;
  const float* bp = bias + lane*NC;
  #pragma unroll
  for (int j = 0; j < NC; ++j) op[j] = reluf(acc[j] + bp[j]);
}

// ---------------- policy final layer: out[v] = p3[v]·w + b ----------------
__global__ void policy_final_kernel(const float* __restrict__ p3, const float* __restrict__ w,
                                    const float* __restrict__ b, float* __restrict__ out, int n){
  int v = blockIdx.x*256 + threadIdx.x;
  if (v >= n) return;
  float acc = b[0];
  const float4* row = (const float4*)(p3 + (size_t)v*32);
  #pragma unroll
  for (int q = 0; q < 8; ++q){
    float4 x = row[q];
    acc += x.x*w[q*4+0] + x.y*w[q*4+1] + x.z*w[q*4+2] + x.w*w[q*4+3];
  }
  out[v] = acc;
}

// ---------------- graph boundaries (batch is sorted) ----------------
__global__ void bounds_kernel(const int* __restrict__ batch, int* __restrict__ gstart,
                              int n, int G){
  int g = threadIdx.x;
  if (g > G) return;
  int lo = 0, hi = n;
  while (lo < hi){ int mid = (lo + hi) >> 1; if (batch[mid] < g) lo = mid + 1; else hi = mid; }
  gstart[g] = lo;
}

// ---------------- global add pool ----------------
__global__ __launch_bounds__(256) void pool_kernel(const float* __restrict__ x,
    const int* __restrict__ gstart, float* __restrict__ pooled){
  int g = blockIdx.x, t = threadIdx.x;
  int f = t & 127, half = t >> 7;
  int beg = gstart[g], end = gstart[g+1];
  float acc = 0.f;
  for (int r = beg + half; r < end; r += 2) acc += x[(size_t)r*128 + f];
  __shared__ float sm[256];
  sm[t] = acc; __syncthreads();
  if (t < 128) pooled[g*128 + t] = sm[t] + sm[t + 128];
}

// ---------------- value MLP (64 rows, tiny) ----------------
__global__ __launch_bounds__(128) void value_mlp_kernel(const float* __restrict__ pooled,
    const float* __restrict__ W0, const float* __restrict__ B0,
    const float* __restrict__ W1, const float* __restrict__ B1,
    const float* __restrict__ W2, const float* __restrict__ B2,
    const float* __restrict__ W3, const float* __restrict__ B3,
    float* __restrict__ outv){
  __shared__ float a[128], b[128];
  int g = blockIdx.x, t = threadIdx.x;
  a[t] = pooled[g*128 + t];
  __syncthreads();
  float acc = B0[t];
  for (int k = 0; k < 128; ++k) acc += a[k]*W0[k*128 + t];
  b[t] = reluf(acc);
  __syncthreads();
  if (t < 64){ acc = B1[t]; for (int k = 0; k < 128; ++k) acc += b[k]*W1[k*64 + t]; a[t] = reluf(acc); }
  __syncthreads();
  if (t < 32){ acc = B2[t]; for (int k = 0; k < 64; ++k) acc += a[k]*W2[k*32 + t]; b[t] = reluf(acc); }
  __syncthreads();
  if (t == 0){ acc = B3[0]; for (int k = 0; k < 32; ++k) acc += b[k]*W3[k]; outv[g] = acc; }
}

extern "C" void kernel_launch(void* const* d_in, const int* in_sizes, int n_in,
                              void* d_out, int out_size, void* d_ws, size_t ws_size,
                              hipStream_t stream){
  const float* x     = (const float*)d_in[0];
  const int*   ei    = (const int*)d_in[1];
  const int*   batch = (const int*)d_in[2];
  const float* W1 = (const float*)d_in[3];
  const float* as1= (const float*)d_in[4];
  const float* ad1= (const float*)d_in[5];
  const float* b1 = (const float*)d_in[6];
  const float* W2 = (const float*)d_in[7];
  const float* as2= (const float*)d_in[8];
  const float* ad2= (const float*)d_in[9];
  const float* b2 = (const float*)d_in[10];
  const float* W3 = (const float*)d_in[11];
  const float* as3= (const float*)d_in[12];
  const float* ad3= (const float*)d_in[13];
  const float* b3 = (const float*)d_in[14];
  const float* pW0= (const float*)d_in[15];
  const float* pb0= (const float*)d_in[16];
  const float* pW1= (const float*)d_in[17];
  const float* pb1= (const float*)d_in[18];
  const float* pW2= (const float*)d_in[19];
  const float* pb2= (const float*)d_in[20];
  const float* pW3= (const float*)d_in[21];
  const float* pb3= (const float*)d_in[22];
  const float* vW0= (const float*)d_in[23];
  const float* vb0= (const float*)d_in[24];
  const float* vW1= (const float*)d_in[25];
  const float* vb1= (const float*)d_in[26];
  const float* vW2= (const float*)d_in[27];
  const float* vb2= (const float*)d_in[28];
  const float* vW3= (const float*)d_in[29];
  const float* vb3= (const float*)d_in[30];
  float* out = (float*)d_out;

  // -------- workspace carve (~260 MB) --------
  char* ws = (char*)d_ws;
  size_t off = 0;
  auto carve = [&](size_t bytes)->char*{
    char* p = ws + off; off = (off + bytes + 255) & ~(size_t)255; return p;
  };
  int*   head   = (int*)  carve((size_t)N_NODES*4);
  int*   nxt    = (int*)  carve((size_t)N_EDGES*4);
  float* s      = (float*)carve((size_t)N_NODES*4);
  float* dsc    = (float*)carve((size_t)N_NODES*4);
  float* wa_s   = (float*)carve(256*4);
  float* wa_d   = (float*)carve(256*4);
  int*   gstart = (int*)  carve(65*4);
  float* pooled = (float*)carve((size_t)N_GRAPHS*128*4);
  float* buf_h  = (float*)carve((size_t)N_NODES*256*4);  // h of current layer (and MLP p1/p2)
  float* buf_a  = (float*)carve((size_t)N_NODES*256*4);  // out1, later out3
  float* buf_b  = (float*)carve((size_t)N_NODES*128*4);  // out2, later p3

  const int* esrc = ei;              // edge_index[0]
  const int* edst = ei + N_EDGES;    // edge_index[1]

  // adjacency lists (rebuilt every launch; ws is re-poisoned)
  init_head_kernel<<<(N_NODES+255)/256, 256, 0, stream>>>(head, N_NODES);
  build_list_kernel<<<(N_EDGES+255)/256, 256, 0, stream>>>(edst, head, nxt, N_EDGES);
  bounds_kernel<<<1, 128, 0, stream>>>(batch, gstart, N_NODES, N_GRAPHS);

  const int GB = (N_NODES + 63) / 64;       // 1563 row-blocks
  const int NB4 = (N_NODES + 3) / 4;        // wave-per-node grids

  // ---- layer 1: x[N,59] -> h buf_h[N,256] -> out buf_a
  wa_kernel<<<1, 256, 0, stream>>>(W1, as1, ad1, wa_s, wa_d, 59, 256);
  gemm_kernel<<<dim3(GB,4), 256, 0, stream>>>(x, W1, nullptr, buf_h, N_NODES, 59, 256, 0);
  sd_kernel<<<NB4, 256, 0, stream>>>(x, wa_s, wa_d, s, dsc, N_NODES, 59);
  agg_kernel<4><<<NB4, 256, 0, stream>>>(buf_h, s, dsc, head, nxt, esrc, b1, buf_a, N_NODES);

  // ---- layer 2: buf_a[N,256] -> h buf_h[N,128] -> out buf_b
  wa_kernel<<<1, 256, 0, stream>>>(W2, as2, ad2, wa_s, wa_d, 256, 128);
  gemm_kernel<<<dim3(GB,2), 256, 0, stream>>>(buf_a, W2, nullptr, buf_h, N_NODES, 256, 128, 0);
  sd_kernel<<<NB4, 256, 0, stream>>>(buf_a, wa_s, wa_d, s, dsc, N_NODES, 256);
  agg_kernel<2><<<NB4, 256, 0, stream>>>(buf_h, s, dsc, head, nxt, esrc, b2, buf_b, N_NODES);

  // ---- layer 3: buf_b[N,128] -> h buf_h[N,128] -> out buf_a
  wa_kernel<<<1, 256, 0, stream>>>(W3, as3, ad3, wa_s, wa_d, 128, 128);
  gemm_kernel<<<dim3(GB,2), 256, 0, stream>>>(buf_b, W3, nullptr, buf_h, N_NODES, 128, 128, 0);
  sd_kernel<<<NB4, 256, 0, stream>>>(buf_b, wa_s, wa_d, s, dsc, N_NODES, 128);
  agg_kernel<2><<<NB4, 256, 0, stream>>>(buf_h, s, dsc, head, nxt, esrc, b3, buf_a, N_NODES);

  // ---- policy MLP: buf_a -> p1 -> p2 -> p3 -> out[0..N)
  float* p1 = buf_h;                         // [N,128]
  float* p2 = buf_h + (size_t)N_NODES*128;   // [N,64]
  float* p3 = buf_b;                         // [N,32]
  gemm_kernel<<<dim3(GB,2), 256, 0, stream>>>(buf_a, pW0, pb0, p1, N_NODES, 128, 128, 1);
  gemm_kernel<<<dim3(GB,1), 256, 0, stream>>>(p1, pW1, pb1, p2, N_NODES, 128, 64, 1);
  gemm_kernel<<<dim3(GB,1), 256, 0, stream>>>(p2, pW2, pb2, p3, N_NODES, 64, 32, 1);
  policy_final_kernel<<<(N_NODES+255)/256, 256, 0, stream>>>(p3, pW3, pb3, out, N_NODES);

  // ---- pool + value MLP -> out[N..N+64)
  pool_kernel<<<N_GRAPHS, 256, 0, stream>>>(buf_a, gstart, pooled);
  value_mlp_kernel<<<N_GRAPHS, 128, 0, stream>>>(pooled, vW0, vb0, vW1, vb1, vW2, vb2, vW3, vb3,
                                                 out + N_NODES);
}

// Round 5
// 1040.248 us; speedup vs baseline: 1.4426x; 1.4426x over previous
//
#include <hip/hip_runtime.h>
#include <hip/hip_bf16.h>
#include <cstdint>

#define N_NODES 100000
#define N_EDGES 800000
#define N_GRAPHS 64

__device__ __forceinline__ float leakyf(float x){ return x >= 0.0f ? x : 0.2f*x; }
__device__ __forceinline__ float reluf(float x){ return x > 0.0f ? x : 0.0f; }

__device__ __forceinline__ float bf2f(unsigned short u){
  union { uint32_t i; float f; } c; c.i = ((uint32_t)u) << 16; return c.f;
}
__device__ __forceinline__ unsigned short f2bf(float x){
  union { float f; uint32_t i; } c; c.f = x;
  uint32_t r = c.i + 0x7FFFu + ((c.i >> 16) & 1u);   // round-to-nearest-even
  return (unsigned short)(r >> 16);
}

// ================= CSR build =================
__global__ void zero_deg_kernel(int* __restrict__ deg, int n){
  int v = blockIdx.x*256 + threadIdx.x;
  if (v < n) deg[v] = 0;
}
__global__ void count_kernel(const int* __restrict__ dst, int* __restrict__ deg,
                             int* __restrict__ pos, int E){
  int e = blockIdx.x*256 + threadIdx.x;
  if (e < E) pos[e] = atomicAdd(&deg[dst[e]], 1);
}
// Hillis-Steele block scan: rowptr[i] = exclusive scan of deg within block; bsum[b]=block total
__global__ __launch_bounds__(256) void scan1_kernel(const int* __restrict__ deg,
    int* __restrict__ rowptr, int* __restrict__ bsum, int n){
  __shared__ int sm[256];
  int t = threadIdx.x, i = blockIdx.x*256 + t;
  int v = (i < n) ? deg[i] : 0;
  sm[t] = v; __syncthreads();
  for (int off = 1; off < 256; off <<= 1){
    int x = (t >= off) ? sm[t-off] : 0;
    __syncthreads();
    sm[t] += x;
    __syncthreads();
  }
  if (i < n) rowptr[i] = sm[t] - v;
  if (t == 255) bsum[blockIdx.x] = sm[255];
}
__global__ __launch_bounds__(512) void scan2_kernel(int* __restrict__ bsum, int nb){
  __shared__ int sm[512];
  int t = threadIdx.x;
  int v = (t < nb) ? bsum[t] : 0;
  sm[t] = v; __syncthreads();
  for (int off = 1; off < 512; off <<= 1){
    int x = (t >= off) ? sm[t-off] : 0;
    __syncthreads();
    sm[t] += x;
    __syncthreads();
  }
  if (t < nb) bsum[t] = sm[t] - v;
}
__global__ void scan3_kernel(int* __restrict__ rowptr, const int* __restrict__ bsum, int n){
  int i = blockIdx.x*256 + threadIdx.x;
  if (i < n) rowptr[i] += bsum[blockIdx.x];
}
__global__ void scatter_kernel(const int* __restrict__ src, const int* __restrict__ dst,
                               const int* __restrict__ rowptr, const int* __restrict__ pos,
                               int* __restrict__ csr, int E){
  int e = blockIdx.x*256 + threadIdx.x;
  if (e < E) csr[rowptr[dst[e]] + pos[e]] = src[e];
}

// ================= Wa = W @ a (tiny) =================
__global__ void wa_kernel(const float* __restrict__ W, const float* __restrict__ a_src,
                          const float* __restrict__ a_dst, float* __restrict__ wa_s,
                          float* __restrict__ wa_d, int K, int Do){
  int k = blockIdx.x*blockDim.x + threadIdx.x;
  if (k >= K) return;
  float ss = 0.f, dd = 0.f;
  const float* wr = W + (size_t)k*Do;
  for (int o = 0; o < Do; ++o){ float w = wr[o]; ss += w*a_src[o]; dd += w*a_dst[o]; }
  wa_s[k] = ss; wa_d[k] = dd;
}

// ================= per-node scores =================
__global__ __launch_bounds__(256) void sd_kernel(const float* __restrict__ in,
    const float* __restrict__ wa_s, const float* __restrict__ wa_d,
    float* __restrict__ s, float* __restrict__ d, int n, int K){
  int wid = threadIdx.x >> 6, lane = threadIdx.x & 63;
  int v = (blockIdx.x << 2) + wid;
  if (v >= n) return;
  float ss = 0.f, dd = 0.f;
  const float* row = in + (size_t)v*K;
  for (int k = lane; k < K; k += 64){ float x = row[k]; ss += x*wa_s[k]; dd += x*wa_d[k]; }
  for (int off = 32; off; off >>= 1){ ss += __shfl_down(ss, off); dd += __shfl_down(dd, off); }
  if (lane == 0){ s[v] = ss; d[v] = dd; }
}

// ================= generic f32 GEMM (f32 or bf16 output) =================
template<int OBF>
__global__ __launch_bounds__(256) void gemm_kernel(
    const float* __restrict__ A, const float* __restrict__ W,
    const float* __restrict__ bias, void* __restrict__ Cv,
    int M, int K, int N, int act){
  __shared__ float As[16][68];
  __shared__ float Ws[16][64];
  const int t  = threadIdx.x;
  const int tn = t & 15, tm = t >> 4;
  const int row0 = blockIdx.x * 64;
  const int col0 = blockIdx.y * 64;
  float acc[4][4] = {};
  for (int k0 = 0; k0 < K; k0 += 16){
    #pragma unroll
    for (int i = 0; i < 4; ++i){
      int idx = t + i*256;
      int m = idx >> 4, k = idx & 15;
      int r = row0 + m, kk = k0 + k;
      float val = 0.f;
      if (r < M && kk < K) val = A[(size_t)r*K + kk];
      As[k][m] = val;
    }
    {
      int k = t >> 4, n4 = (t & 15) * 4;
      int kk = k0 + k, c = col0 + n4;
      float4 wv = make_float4(0.f,0.f,0.f,0.f);
      if (kk < K && c + 3 < N) wv = *(const float4*)&W[(size_t)kk*N + c];
      *(float4*)&Ws[k][n4] = wv;
    }
    __syncthreads();
    #pragma unroll
    for (int kk = 0; kk < 16; ++kk){
      const float4 a = *(const float4*)&As[kk][tm*4];
      const float4 w = *(const float4*)&Ws[kk][tn*4];
      acc[0][0] += a.x*w.x; acc[0][1] += a.x*w.y; acc[0][2] += a.x*w.z; acc[0][3] += a.x*w.w;
      acc[1][0] += a.y*w.x; acc[1][1] += a.y*w.y; acc[1][2] += a.y*w.z; acc[1][3] += a.y*w.w;
      acc[2][0] += a.z*w.x; acc[2][1] += a.z*w.y; acc[2][2] += a.z*w.z; acc[2][3] += a.z*w.w;
      acc[3][0] += a.w*w.x; acc[3][1] += a.w*w.y; acc[3][2] += a.w*w.z; acc[3][3] += a.w*w.w;
    }
    __syncthreads();
  }
  const int c = col0 + tn*4;
  if (c >= N) return;
  #pragma unroll
  for (int i = 0; i < 4; ++i){
    int r = row0 + tm*4 + i;
    if (r >= M) continue;
    float vals[4];
    #pragma unroll
    for (int j = 0; j < 4; ++j){
      float val = acc[i][j];
      if (bias) val += bias[c + j];
      if (act) val = reluf(val);
      vals[j] = val;
    }
    if constexpr (OBF == 0){
      float* C = (float*)Cv;
      *(float4*)&C[(size_t)r*N + c] = make_float4(vals[0], vals[1], vals[2], vals[3]);
    } else {
      unsigned short* C = (unsigned short*)Cv;
      *(ushort4*)&C[(size_t)r*N + c] =
        make_ushort4(f2bf(vals[0]), f2bf(vals[1]), f2bf(vals[2]), f2bf(vals[3]));
    }
  }
}

// ================= CSR edge-softmax aggregation, h in bf16 =================
template<int NC>
__device__ __forceinline__ void load_row(const unsigned short* p, float* f){
  if constexpr (NC == 2){
    uint32_t u = *(const uint32_t*)p;
    union { uint32_t i; float ff; } a, b;
    a.i = u << 16; b.i = u & 0xFFFF0000u;
    f[0] = a.ff; f[1] = b.ff;
  } else {
    uint2 u = *(const uint2*)p;
    union { uint32_t i; float ff; } a, b, c, d;
    a.i = u.x << 16; b.i = u.x & 0xFFFF0000u;
    c.i = u.y << 16; d.i = u.y & 0xFFFF0000u;
    f[0] = a.ff; f[1] = b.ff; f[2] = c.ff; f[3] = d.ff;
  }
}

template<int NC>   // Do = NC*64
__global__ __launch_bounds__(256) void agg_csr_kernel(
    const unsigned short* __restrict__ h, const float* __restrict__ s,
    const float* __restrict__ dsc, const int* __restrict__ rowptr,
    const int* __restrict__ deg, const int* __restrict__ csr, float* __restrict__ ew,
    const float* __restrict__ bias, float* __restrict__ out, int n){
  const int Do = NC*64;
  int wid = threadIdx.x >> 6, lane = threadIdx.x & 63;
  int v = (blockIdx.x << 2) + wid;
  if (v >= n) return;
  const int beg = rowptr[v];
  const int dg  = deg[v];
  const float dv = dsc[v];
  const float e0 = leakyf(s[v] + dv);
  float acc[NC];

  if (dg <= 64){
    // ---- fully in-register path (typical: Poisson(8) degrees) ----
    int srcl = 0; float sc = -1e30f;
    if (lane < dg){ srcl = csr[beg + lane]; sc = leakyf(s[srcl] + dv); }
    float mm = sc;
    #pragma unroll
    for (int off = 32; off; off >>= 1) mm = fmaxf(mm, __shfl_xor(mm, off));
    const float m = fmaxf(e0, mm);
    float w = (lane < dg) ? __expf(sc - m) : 0.f;
    float den = w;
    #pragma unroll
    for (int off = 32; off; off >>= 1) den += __shfl_xor(den, off);
    const float ws0 = __expf(e0 - m);
    den += ws0;
    const float inv = 1.0f / (den + 1e-16f);
    const float wl = w * inv;
    {
      const float w0 = ws0 * inv;
      const unsigned short* hp = h + (size_t)v*Do + lane*NC;
      float f[NC]; load_row<NC>(hp, f);
      #pragma unroll
      for (int c2 = 0; c2 < NC; ++c2) acc[c2] = w0 * f[c2];
    }
    int j = 0;
    for (; j + 4 <= dg; j += 4){
      int  s0 = __shfl(srcl, j),   s1 = __shfl(srcl, j+1);
      int  s2 = __shfl(srcl, j+2), s3 = __shfl(srcl, j+3);
      float w0_ = __shfl(wl, j),   w1_ = __shfl(wl, j+1);
      float w2_ = __shfl(wl, j+2), w3_ = __shfl(wl, j+3);
      float f0[NC], f1[NC], f2[NC], f3[NC];
      load_row<NC>(h + (size_t)s0*Do + lane*NC, f0);
      load_row<NC>(h + (size_t)s1*Do + lane*NC, f1);
      load_row<NC>(h + (size_t)s2*Do + lane*NC, f2);
      load_row<NC>(h + (size_t)s3*Do + lane*NC, f3);
      #pragma unroll
      for (int c2 = 0; c2 < NC; ++c2)
        acc[c2] += w0_*f0[c2] + w1_*f1[c2] + w2_*f2[c2] + w3_*f3[c2];
    }
    for (; j < dg; ++j){
      int src = __shfl(srcl, j);
      float w_ = __shfl(wl, j);
      float f[NC]; load_row<NC>(h + (size_t)src*Do + lane*NC, f);
      #pragma unroll
      for (int c2 = 0; c2 < NC; ++c2) acc[c2] += w_*f[c2];
    }
  } else {
    // ---- general chunked path (spills scores to ew) ----
    float m = e0;
    for (int base = 0; base < dg; base += 64){
      int i = base + lane; float sc = -1e30f;
      if (i < dg){ int src = csr[beg + i]; sc = leakyf(s[src] + dv); ew[beg + i] = sc; }
      #pragma unroll
      for (int off = 32; off; off >>= 1) sc = fmaxf(sc, __shfl_xor(sc, off));
      m = fmaxf(m, sc);
    }
    float dsum = 0.f;
    for (int base = 0; base < dg; base += 64){
      int i = base + lane; float w = 0.f;
      if (i < dg){ w = __expf(ew[beg + i] - m); ew[beg + i] = w; }
      float cs = w;
      #pragma unroll
      for (int off = 32; off; off >>= 1) cs += __shfl_xor(cs, off);
      dsum += cs;
    }
    const float ws0 = __expf(e0 - m);
    const float inv = 1.0f / (dsum + ws0 + 1e-16f);
    {
      const float w0 = ws0 * inv;
      float f[NC]; load_row<NC>(h + (size_t)v*Do + lane*NC, f);
      #pragma unroll
      for (int c2 = 0; c2 < NC; ++c2) acc[c2] = w0 * f[c2];
    }
    for (int base = 0; base < dg; base += 64){
      int i = base + lane;
      int srcl = 0; float wl = 0.f;
      if (i < dg){ srcl = csr[beg + i]; wl = ew[beg + i] * inv; }
      int cnt = min(64, dg - base);
      for (int j = 0; j < cnt; ++j){
        int src = __shfl(srcl, j);
        float w_ = __shfl(wl, j);
        float f[NC]; load_row<NC>(h + (size_t)src*Do + lane*NC, f);
        #pragma unroll
        for (int c2 = 0; c2 < NC; ++c2) acc[c2] += w_*f[c2];
      }
    }
  }

  float* op = out + (size_t)v*Do + lane*NC;
  const float* bp = bias + lane*NC;
  #pragma unroll
  for (int c2 = 0; c2 < NC; ++c2) op[c2] = reluf(acc[c2] + bp[c2]);
}

// ================= policy final layer =================
__global__ void policy_final_kernel(const float* __restrict__ p3, const float* __restrict__ w,
                                    const float* __restrict__ b, float* __restrict__ out, int n){
  int v = blockIdx.x*256 + threadIdx.x;
  if (v >= n) return;
  float acc = b[0];
  const float4* row = (const float4*)(p3 + (size_t)v*32);
  #pragma unroll
  for (int q = 0; q < 8; ++q){
    float4 x = row[q];
    acc += x.x*w[q*4+0] + x.y*w[q*4+1] + x.z*w[q*4+2] + x.w*w[q*4+3];
  }
  out[v] = acc;
}

// ================= graph boundaries =================
__global__ void bounds_kernel(const int* __restrict__ batch, int* __restrict__ gstart,
                              int n, int G){
  int g = threadIdx.x;
  if (g > G) return;
  int lo = 0, hi = n;
  while (lo < hi){ int mid = (lo + hi) >> 1; if (batch[mid] < g) lo = mid + 1; else hi = mid; }
  gstart[g] = lo;
}

// ================= global add pool =================
__global__ __launch_bounds__(256) void pool_kernel(const float* __restrict__ x,
    const int* __restrict__ gstart, float* __restrict__ pooled){
  int g = blockIdx.x, t = threadIdx.x;
  int f = t & 127, half = t >> 7;
  int beg = gstart[g], end = gstart[g+1];
  float acc = 0.f;
  for (int r = beg + half; r < end; r += 2) acc += x[(size_t)r*128 + f];
  __shared__ float sm[256];
  sm[t] = acc; __syncthreads();
  if (t < 128) pooled[g*128 + t] = sm[t] + sm[t + 128];
}

// ================= value MLP =================
__global__ __launch_bounds__(128) void value_mlp_kernel(const float* __restrict__ pooled,
    const float* __restrict__ W0, const float* __restrict__ B0,
    const float* __restrict__ W1, const float* __restrict__ B1,
    const float* __restrict__ W2, const float* __restrict__ B2,
    const float* __restrict__ W3, const float* __restrict__ B3,
    float* __restrict__ outv){
  __shared__ float a[128], b[128];
  int g = blockIdx.x, t = threadIdx.x;
  a[t] = pooled[g*128 + t];
  __syncthreads();
  float acc = B0[t];
  for (int k = 0; k < 128; ++k) acc += a[k]*W0[k*128 + t];
  b[t] = reluf(acc);
  __syncthreads();
  if (t < 64){ acc = B1[t]; for (int k = 0; k < 128; ++k) acc += b[k]*W1[k*64 + t]; a[t] = reluf(acc); }
  __syncthreads();
  if (t < 32){ acc = B2[t]; for (int k = 0; k < 64; ++k) acc += a[k]*W2[k*32 + t]; b[t] = reluf(acc); }
  __syncthreads();
  if (t == 0){ acc = B3[0]; for (int k = 0; k < 32; ++k) acc += b[k]*W3[k]; outv[g] = acc; }
}

extern "C" void kernel_launch(void* const* d_in, const int* in_sizes, int n_in,
                              void* d_out, int out_size, void* d_ws, size_t ws_size,
                              hipStream_t stream){
  const float* x     = (const float*)d_in[0];
  const int*   ei    = (const int*)d_in[1];
  const int*   batch = (const int*)d_in[2];
  const float* W1 = (const float*)d_in[3];
  const float* as1= (const float*)d_in[4];
  const float* ad1= (const float*)d_in[5];
  const float* b1 = (const float*)d_in[6];
  const float* W2 = (const float*)d_in[7];
  const float* as2= (const float*)d_in[8];
  const float* ad2= (const float*)d_in[9];
  const float* b2 = (const float*)d_in[10];
  const float* W3 = (const float*)d_in[11];
  const float* as3= (const float*)d_in[12];
  const float* ad3= (const float*)d_in[13];
  const float* b3 = (const float*)d_in[14];
  const float* pW0= (const float*)d_in[15];
  const float* pb0= (const float*)d_in[16];
  const float* pW1= (const float*)d_in[17];
  const float* pb1= (const float*)d_in[18];
  const float* pW2= (const float*)d_in[19];
  const float* pb2= (const float*)d_in[20];
  const float* pW3= (const float*)d_in[21];
  const float* pb3= (const float*)d_in[22];
  const float* vW0= (const float*)d_in[23];
  const float* vb0= (const float*)d_in[24];
  const float* vW1= (const float*)d_in[25];
  const float* vb1= (const float*)d_in[26];
  const float* vW2= (const float*)d_in[27];
  const float* vb2= (const float*)d_in[28];
  const float* vW3= (const float*)d_in[29];
  const float* vb3= (const float*)d_in[30];
  float* out = (float*)d_out;

  // -------- workspace carve (~220 MB) --------
  char* ws = (char*)d_ws;
  size_t off = 0;
  auto carve = [&](size_t bytes)->char*{
    char* p = ws + off; off = (off + bytes + 255) & ~(size_t)255; return p;
  };
  int*   deg    = (int*)  carve((size_t)N_NODES*4);
  int*   rowptr = (int*)  carve((size_t)(N_NODES+1)*4);
  int*   pos    = (int*)  carve((size_t)N_EDGES*4);
  int*   csr    = (int*)  carve((size_t)N_EDGES*4);
  int*   bsum   = (int*)  carve(512*4);
  float* ew     = (float*)carve((size_t)N_EDGES*4);
  float* s      = (float*)carve((size_t)N_NODES*4);
  float* dsc    = (float*)carve((size_t)N_NODES*4);
  float* wa_s   = (float*)carve(256*4);
  float* wa_d   = (float*)carve(256*4);
  int*   gstart = (int*)  carve(65*4);
  float* pooled = (float*)carve((size_t)N_GRAPHS*128*4);
  unsigned short* hbuf = (unsigned short*)carve((size_t)N_NODES*256*2); // bf16 h (all layers)
  float* buf_a  = (float*)carve((size_t)N_NODES*256*4);  // out1; later out3
  float* buf_b  = (float*)carve((size_t)N_NODES*128*4);  // out2; later p1
  // p2/p3 reuse hbuf's storage after layer-3 h is consumed
  float* p2 = (float*)hbuf;                              // [N,64]  (25.6 MB)
  float* p3 = (float*)(hbuf + (size_t)N_NODES*64*2);     // [N,32]  (12.8 MB), 256B-aligned region

  const int* esrc = ei;              // edge_index[0]
  const int* edst = ei + N_EDGES;    // edge_index[1]

  const int NBn = (N_NODES + 255)/256;   // 391
  const int NBe = (N_EDGES + 255)/256;

  // -------- CSR build --------
  zero_deg_kernel<<<NBn, 256, 0, stream>>>(deg, N_NODES);
  count_kernel<<<NBe, 256, 0, stream>>>(edst, deg, pos, N_EDGES);
  scan1_kernel<<<NBn, 256, 0, stream>>>(deg, rowptr, bsum, N_NODES);
  scan2_kernel<<<1, 512, 0, stream>>>(bsum, NBn);
  scan3_kernel<<<NBn, 256, 0, stream>>>(rowptr, bsum, N_NODES);
  scatter_kernel<<<NBe, 256, 0, stream>>>(esrc, edst, rowptr, pos, csr, N_EDGES);
  bounds_kernel<<<1, 128, 0, stream>>>(batch, gstart, N_NODES, N_GRAPHS);

  const int GB  = (N_NODES + 63) / 64;
  const int NB4 = (N_NODES + 3) / 4;

  // ---- layer 1: x[N,59] -> h(bf16)[N,256] -> out1 buf_a(f32)
  wa_kernel<<<1, 256, 0, stream>>>(W1, as1, ad1, wa_s, wa_d, 59, 256);
  gemm_kernel<1><<<dim3(GB,4), 256, 0, stream>>>(x, W1, nullptr, hbuf, N_NODES, 59, 256, 0);
  sd_kernel<<<NB4, 256, 0, stream>>>(x, wa_s, wa_d, s, dsc, N_NODES, 59);
  agg_csr_kernel<4><<<NB4, 256, 0, stream>>>(hbuf, s, dsc, rowptr, deg, csr, ew, b1, buf_a, N_NODES);

  // ---- layer 2: buf_a[N,256] -> h(bf16)[N,128] -> out2 buf_b
  wa_kernel<<<1, 256, 0, stream>>>(W2, as2, ad2, wa_s, wa_d, 256, 128);
  gemm_kernel<1><<<dim3(GB,2), 256, 0, stream>>>(buf_a, W2, nullptr, hbuf, N_NODES, 256, 128, 0);
  sd_kernel<<<NB4, 256, 0, stream>>>(buf_a, wa_s, wa_d, s, dsc, N_NODES, 256);
  agg_csr_kernel<2><<<NB4, 256, 0, stream>>>(hbuf, s, dsc, rowptr, deg, csr, ew, b2, buf_b, N_NODES);

  // ---- layer 3: buf_b[N,128] -> h(bf16)[N,128] -> out3 buf_a
  wa_kernel<<<1, 256, 0, stream>>>(W3, as3, ad3, wa_s, wa_d, 128, 128);
  gemm_kernel<1><<<dim3(GB,2), 256, 0, stream>>>(buf_b, W3, nullptr, hbuf, N_NODES, 128, 128, 0);
  sd_kernel<<<NB4, 256, 0, stream>>>(buf_b, wa_s, wa_d, s, dsc, N_NODES, 128);
  agg_csr_kernel<2><<<NB4, 256, 0, stream>>>(hbuf, s, dsc, rowptr, deg, csr, ew, b3, buf_a, N_NODES);

  // ---- policy MLP: out3(buf_a) -> p1(buf_b) -> p2 -> p3 -> out[0..N)
  gemm_kernel<0><<<dim3(GB,2), 256, 0, stream>>>(buf_a, pW0, pb0, buf_b, N_NODES, 128, 128, 1);
  gemm_kernel<0><<<dim3(GB,1), 256, 0, stream>>>(buf_b, pW1, pb1, p2, N_NODES, 128, 64, 1);
  gemm_kernel<0><<<dim3(GB,1), 256, 0, stream>>>(p2, pW2, pb2, p3, N_NODES, 64, 32, 1);
  policy_final_kernel<<<NBn, 256, 0, stream>>>(p3, pW3, pb3, out, N_NODES);

  // ---- pool + value MLP -> out[N..N+64)
  pool_kernel<<<N_GRAPHS, 256, 0, stream>>>(buf_a, gstart, pooled);
  value_mlp_kernel<<<N_GRAPHS, 128, 0, stream>>>(pooled, vW0, vb0, vW1, vb1, vW2, vb2, vW3, vb3,
                                                 out + N_NODES);
}

// Round 6
// 734.519 us; speedup vs baseline: 2.0430x; 1.4162x over previous
//
#include <hip/hip_runtime.h>
#include <hip/hip_bf16.h>
#include <cstdint>

#define N_NODES 100000
#define N_EDGES 800000
#define N_GRAPHS 64
#define POOL_SPLIT 16

typedef short short8 __attribute__((ext_vector_type(8)));
typedef float f32x4 __attribute__((ext_vector_type(4)));

__device__ __forceinline__ float leakyf(float x){ return x >= 0.0f ? x : 0.2f*x; }
__device__ __forceinline__ float reluf(float x){ return x > 0.0f ? x : 0.0f; }

__device__ __forceinline__ float bf2f(unsigned short u){
  union { uint32_t i; float f; } c; c.i = ((uint32_t)u) << 16; return c.f;
}
__device__ __forceinline__ unsigned short f2bf(float x){
  union { float f; uint32_t i; } c; c.f = x;
  uint32_t r = c.i + 0x7FFFu + ((c.i >> 16) & 1u);   // round-to-nearest-even
  return (unsigned short)(r >> 16);
}

// ================= CSR build =================
__global__ void zero_deg_kernel(int* __restrict__ deg, int n){
  int v = blockIdx.x*256 + threadIdx.x;
  if (v < n) deg[v] = 0;
}
__global__ void count_kernel(const int* __restrict__ dst, int* __restrict__ deg,
                             int* __restrict__ pos, int E){
  int e = blockIdx.x*256 + threadIdx.x;
  if (e < E) pos[e] = atomicAdd(&deg[dst[e]], 1);
}
__global__ __launch_bounds__(256) void scan1_kernel(const int* __restrict__ deg,
    int* __restrict__ rowptr, int* __restrict__ bsum, int n){
  __shared__ int sm[256];
  int t = threadIdx.x, i = blockIdx.x*256 + t;
  int v = (i < n) ? deg[i] : 0;
  sm[t] = v; __syncthreads();
  for (int off = 1; off < 256; off <<= 1){
    int x = (t >= off) ? sm[t-off] : 0;
    __syncthreads();
    sm[t] += x;
    __syncthreads();
  }
  if (i < n) rowptr[i] = sm[t] - v;
  if (t == 255) bsum[blockIdx.x] = sm[255];
}
__global__ __launch_bounds__(512) void scan2_kernel(int* __restrict__ bsum, int nb){
  __shared__ int sm[512];
  int t = threadIdx.x;
  int v = (t < nb) ? bsum[t] : 0;
  sm[t] = v; __syncthreads();
  for (int off = 1; off < 512; off <<= 1){
    int x = (t >= off) ? sm[t-off] : 0;
    __syncthreads();
    sm[t] += x;
    __syncthreads();
  }
  if (t < nb) bsum[t] = sm[t] - v;
}
__global__ void scan3_kernel(int* __restrict__ rowptr, const int* __restrict__ bsum, int n){
  int i = blockIdx.x*256 + threadIdx.x;
  if (i < n) rowptr[i] += bsum[blockIdx.x];
}
__global__ void scatter_kernel(const int* __restrict__ src, const int* __restrict__ dst,
                               const int* __restrict__ rowptr, const int* __restrict__ pos,
                               int* __restrict__ csr, int E){
  int e = blockIdx.x*256 + threadIdx.x;
  if (e < E) csr[rowptr[dst[e]] + pos[e]] = src[e];
}

// ================= Wa = W @ a (tiny) =================
__global__ void wa_kernel(const float* __restrict__ W, const float* __restrict__ a_src,
                          const float* __restrict__ a_dst, float* __restrict__ wa_s,
                          float* __restrict__ wa_d, int K, int Do){
  int k = blockIdx.x*blockDim.x + threadIdx.x;
  if (k >= K) return;
  float ss = 0.f, dd = 0.f;
  const float* wr = W + (size_t)k*Do;
  for (int o = 0; o < Do; ++o){ float w = wr[o]; ss += w*a_src[o]; dd += w*a_dst[o]; }
  wa_s[k] = ss; wa_d[k] = dd;
}

// ================= per-node scores =================
__global__ __launch_bounds__(256) void sd_kernel(const float* __restrict__ in,
    const float* __restrict__ wa_s, const float* __restrict__ wa_d,
    float* __restrict__ s, float* __restrict__ d, int n, int K){
  int wid = threadIdx.x >> 6, lane = threadIdx.x & 63;
  int v = (blockIdx.x << 2) + wid;
  if (v >= n) return;
  float ss = 0.f, dd = 0.f;
  const float* row = in + (size_t)v*K;
  for (int k = lane; k < K; k += 64){ float x = row[k]; ss += x*wa_s[k]; dd += x*wa_d[k]; }
  for (int off = 32; off; off >>= 1){ ss += __shfl_down(ss, off); dd += __shfl_down(dd, off); }
  if (lane == 0){ s[v] = ss; d[v] = dd; }
}

// ================= MFMA bf16 GEMM: C = A[MxK] @ W[KxN] (+bias)(+relu) =================
// 64x64 tile, BK=32, 4 waves in 2x2 grid, each wave 32x32 = 2x2 16x16x32 fragments.
// Requires N % 64 == 0. A,W are f32 in global, converted to bf16 at staging.
template<int OBF>   // 0: f32 out, 1: bf16 out
__global__ __launch_bounds__(256) void gemm_mfma(
    const float* __restrict__ A, const float* __restrict__ W,
    const float* __restrict__ bias, void* __restrict__ Cv,
    int M, int K, int N, int act){
  // padded stride 40 shorts (80B = 20 banks): row-major reads are 2-way conflicts (free)
  __shared__ short As[64][40];   // [m][k]
  __shared__ short Bs[64][40];   // [n][k]  (transposed: k contiguous per col)
  const int t = threadIdx.x;
  const int row0 = blockIdx.x * 64;
  const int col0 = blockIdx.y * 64;
  const int wv = t >> 6, lane = t & 63;
  const int wr = wv >> 1, wc = wv & 1;       // wave's 32x32 quadrant
  const int lr = lane & 15, lg = lane >> 4;  // fragment lane row/col + k-group

  f32x4 acc00 = {}, acc01 = {}, acc10 = {}, acc11 = {};

  const bool k4ok = (K % 4) == 0;
  for (int k0 = 0; k0 < K; k0 += 32){
    // ---- stage A: thread t -> row m=t>>2, k-quarter kq=(t&3)*8
    {
      int m = t >> 2, kq = (t & 3) * 8;
      int gr = row0 + m;
      short8 av;
      if (gr < M && k4ok && (k0 + kq + 7) < K){
        const float4 f0 = *(const float4*)&A[(size_t)gr*K + k0 + kq];
        const float4 f1 = *(const float4*)&A[(size_t)gr*K + k0 + kq + 4];
        av[0]=f2bf(f0.x); av[1]=f2bf(f0.y); av[2]=f2bf(f0.z); av[3]=f2bf(f0.w);
        av[4]=f2bf(f1.x); av[5]=f2bf(f1.y); av[6]=f2bf(f1.z); av[7]=f2bf(f1.w);
      } else {
        #pragma unroll
        for (int j = 0; j < 8; ++j){
          int gk = k0 + kq + j;
          float val = (gr < M && gk < K) ? A[(size_t)gr*K + gk] : 0.f;
          av[j] = f2bf(val);
        }
      }
      *(short8*)&As[m][kq] = av;
    }
    // ---- stage B (transposed): thread t -> col n=t&63, k-quarter k8=(t>>6)*8
    {
      int n = t & 63, k8 = (t >> 6) * 8;
      short8 bv;
      #pragma unroll
      for (int j = 0; j < 8; ++j){
        int gk = k0 + k8 + j;
        float val = (gk < K) ? W[(size_t)gk*N + col0 + n] : 0.f;
        bv[j] = f2bf(val);
      }
      *(short8*)&Bs[n][k8] = bv;
    }
    __syncthreads();
    // ---- MFMA: A lane: row=lr, k=lg*8+j ; B lane: col=lr, k=lg*8+j
    short8 af0 = *(short8*)&As[wr*32 +  0 + lr][lg*8];
    short8 af1 = *(short8*)&As[wr*32 + 16 + lr][lg*8];
    short8 bf0 = *(short8*)&Bs[wc*32 +  0 + lr][lg*8];
    short8 bf1 = *(short8*)&Bs[wc*32 + 16 + lr][lg*8];
    acc00 = __builtin_amdgcn_mfma_f32_16x16x32_bf16(af0, bf0, acc00, 0, 0, 0);
    acc01 = __builtin_amdgcn_mfma_f32_16x16x32_bf16(af0, bf1, acc01, 0, 0, 0);
    acc10 = __builtin_amdgcn_mfma_f32_16x16x32_bf16(af1, bf0, acc10, 0, 0, 0);
    acc11 = __builtin_amdgcn_mfma_f32_16x16x32_bf16(af1, bf1, acc11, 0, 0, 0);
    __syncthreads();
  }

  // ---- C write: lane l, reg j -> row=(l>>4)*4+j, col=l&15 (m89-verified)
  #pragma unroll
  for (int fm = 0; fm < 2; ++fm){
    #pragma unroll
    for (int fn = 0; fn < 2; ++fn){
      const f32x4 a = (fm==0) ? (fn==0 ? acc00 : acc01) : (fn==0 ? acc10 : acc11);
      int col = col0 + wc*32 + fn*16 + lr;
      float bv = bias ? bias[col] : 0.f;
      #pragma unroll
      for (int j = 0; j < 4; ++j){
        int row = row0 + wr*32 + fm*16 + lg*4 + j;
        if (row >= M) continue;
        float val = a[j] + bv;
        if (act) val = reluf(val);
        if constexpr (OBF == 0) ((float*)Cv)[(size_t)row*N + col] = val;
        else ((unsigned short*)Cv)[(size_t)row*N + col] = f2bf(val);
      }
    }
  }
}

// ================= f32 GEMM (kept for tiny N=32 layer) =================
template<int OBF>
__global__ __launch_bounds__(256) void gemm_kernel(
    const float* __restrict__ A, const float* __restrict__ W,
    const float* __restrict__ bias, void* __restrict__ Cv,
    int M, int K, int N, int act){
  __shared__ float Asf[16][68];
  __shared__ float Wsf[16][64];
  const int t  = threadIdx.x;
  const int tn = t & 15, tm = t >> 4;
  const int row0 = blockIdx.x * 64;
  const int col0 = blockIdx.y * 64;
  float acc[4][4] = {};
  for (int k0 = 0; k0 < K; k0 += 16){
    #pragma unroll
    for (int i = 0; i < 4; ++i){
      int idx = t + i*256;
      int m = idx >> 4, k = idx & 15;
      int r = row0 + m, kk = k0 + k;
      float val = 0.f;
      if (r < M && kk < K) val = A[(size_t)r*K + kk];
      Asf[k][m] = val;
    }
    {
      int k = t >> 4, n4 = (t & 15) * 4;
      int kk = k0 + k, c = col0 + n4;
      float4 wv = make_float4(0.f,0.f,0.f,0.f);
      if (kk < K && c + 3 < N) wv = *(const float4*)&W[(size_t)kk*N + c];
      *(float4*)&Wsf[k][n4] = wv;
    }
    __syncthreads();
    #pragma unroll
    for (int kk = 0; kk < 16; ++kk){
      const float4 a = *(const float4*)&Asf[kk][tm*4];
      const float4 w = *(const float4*)&Wsf[kk][tn*4];
      acc[0][0] += a.x*w.x; acc[0][1] += a.x*w.y; acc[0][2] += a.x*w.z; acc[0][3] += a.x*w.w;
      acc[1][0] += a.y*w.x; acc[1][1] += a.y*w.y; acc[1][2] += a.y*w.z; acc[1][3] += a.y*w.w;
      acc[2][0] += a.z*w.x; acc[2][1] += a.z*w.y; acc[2][2] += a.z*w.z; acc[2][3] += a.z*w.w;
      acc[3][0] += a.w*w.x; acc[3][1] += a.w*w.y; acc[3][2] += a.w*w.z; acc[3][3] += a.w*w.w;
    }
    __syncthreads();
  }
  const int c = col0 + tn*4;
  if (c >= N) return;
  #pragma unroll
  for (int i = 0; i < 4; ++i){
    int r = row0 + tm*4 + i;
    if (r >= M) continue;
    float vals[4];
    #pragma unroll
    for (int j = 0; j < 4; ++j){
      float val = acc[i][j];
      if (bias) val += bias[c + j];
      if (act) val = reluf(val);
      vals[j] = val;
    }
    if constexpr (OBF == 0){
      float* C = (float*)Cv;
      *(float4*)&C[(size_t)r*N + c] = make_float4(vals[0], vals[1], vals[2], vals[3]);
    } else {
      unsigned short* C = (unsigned short*)Cv;
      *(ushort4*)&C[(size_t)r*N + c] =
        make_ushort4(f2bf(vals[0]), f2bf(vals[1]), f2bf(vals[2]), f2bf(vals[3]));
    }
  }
}

// ================= CSR edge-softmax aggregation, h in bf16 =================
template<int NC>
__device__ __forceinline__ void load_row(const unsigned short* p, float* f){
  if constexpr (NC == 2){
    uint32_t u = *(const uint32_t*)p;
    union { uint32_t i; float ff; } a, b;
    a.i = u << 16; b.i = u & 0xFFFF0000u;
    f[0] = a.ff; f[1] = b.ff;
  } else {
    uint2 u = *(const uint2*)p;
    union { uint32_t i; float ff; } a, b, c, d;
    a.i = u.x << 16; b.i = u.x & 0xFFFF0000u;
    c.i = u.y << 16; d.i = u.y & 0xFFFF0000u;
    f[0] = a.ff; f[1] = b.ff; f[2] = c.ff; f[3] = d.ff;
  }
}

template<int NC>   // Do = NC*64
__global__ __launch_bounds__(256) void agg_csr_kernel(
    const unsigned short* __restrict__ h, const float* __restrict__ s,
    const float* __restrict__ dsc, const int* __restrict__ rowptr,
    const int* __restrict__ deg, const int* __restrict__ csr, float* __restrict__ ew,
    const float* __restrict__ bias, float* __restrict__ out, int n){
  const int Do = NC*64;
  int wid = threadIdx.x >> 6, lane = threadIdx.x & 63;
  int v = (blockIdx.x << 2) + wid;
  if (v >= n) return;
  const int beg = rowptr[v];
  const int dg  = deg[v];
  const float dv = dsc[v];
  const float e0 = leakyf(s[v] + dv);
  float acc[NC];

  if (dg <= 64){
    int srcl = 0; float sc = -1e30f;
    if (lane < dg){ srcl = csr[beg + lane]; sc = leakyf(s[srcl] + dv); }
    float mm = sc;
    #pragma unroll
    for (int off = 32; off; off >>= 1) mm = fmaxf(mm, __shfl_xor(mm, off));
    const float m = fmaxf(e0, mm);
    float w = (lane < dg) ? __expf(sc - m) : 0.f;
    float den = w;
    #pragma unroll
    for (int off = 32; off; off >>= 1) den += __shfl_xor(den, off);
    const float ws0 = __expf(e0 - m);
    den += ws0;
    const float inv = 1.0f / (den + 1e-16f);
    const float wl = w * inv;
    {
      const float w0 = ws0 * inv;
      const unsigned short* hp = h + (size_t)v*Do + lane*NC;
      float f[NC]; load_row<NC>(hp, f);
      #pragma unroll
      for (int c2 = 0; c2 < NC; ++c2) acc[c2] = w0 * f[c2];
    }
    int j = 0;
    for (; j + 4 <= dg; j += 4){
      int  s0 = __shfl(srcl, j),   s1 = __shfl(srcl, j+1);
      int  s2 = __shfl(srcl, j+2), s3 = __shfl(srcl, j+3);
      float w0_ = __shfl(wl, j),   w1_ = __shfl(wl, j+1);
      float w2_ = __shfl(wl, j+2), w3_ = __shfl(wl, j+3);
      float f0[NC], f1[NC], f2[NC], f3[NC];
      load_row<NC>(h + (size_t)s0*Do + lane*NC, f0);
      load_row<NC>(h + (size_t)s1*Do + lane*NC, f1);
      load_row<NC>(h + (size_t)s2*Do + lane*NC, f2);
      load_row<NC>(h + (size_t)s3*Do + lane*NC, f3);
      #pragma unroll
      for (int c2 = 0; c2 < NC; ++c2)
        acc[c2] += w0_*f0[c2] + w1_*f1[c2] + w2_*f2[c2] + w3_*f3[c2];
    }
    for (; j < dg; ++j){
      int src = __shfl(srcl, j);
      float w_ = __shfl(wl, j);
      float f[NC]; load_row<NC>(h + (size_t)src*Do + lane*NC, f);
      #pragma unroll
      for (int c2 = 0; c2 < NC; ++c2) acc[c2] += w_*f[c2];
    }
  } else {
    float m = e0;
    for (int base = 0; base < dg; base += 64){
      int i = base + lane; float sc = -1e30f;
      if (i < dg){ int src = csr[beg + i]; sc = leakyf(s[src] + dv); ew[beg + i] = sc; }
      #pragma unroll
      for (int off = 32; off; off >>= 1) sc = fmaxf(sc, __shfl_xor(sc, off));
      m = fmaxf(m, sc);
    }
    float dsum = 0.f;
    for (int base = 0; base < dg; base += 64){
      int i = base + lane; float w = 0.f;
      if (i < dg){ w = __expf(ew[beg + i] - m); ew[beg + i] = w; }
      float cs = w;
      #pragma unroll
      for (int off = 32; off; off >>= 1) cs += __shfl_xor(cs, off);
      dsum += cs;
    }
    const float ws0 = __expf(e0 - m);
    const float inv = 1.0f / (dsum + ws0 + 1e-16f);
    {
      const float w0 = ws0 * inv;
      float f[NC]; load_row<NC>(h + (size_t)v*Do + lane*NC, f);
      #pragma unroll
      for (int c2 = 0; c2 < NC; ++c2) acc[c2] = w0 * f[c2];
    }
    for (int base = 0; base < dg; base += 64){
      int i = base + lane;
      int srcl = 0; float wl = 0.f;
      if (i < dg){ srcl = csr[beg + i]; wl = ew[beg + i] * inv; }
      int cnt = min(64, dg - base);
      for (int j = 0; j < cnt; ++j){
        int src = __shfl(srcl, j);
        float w_ = __shfl(wl, j);
        float f[NC]; load_row<NC>(h + (size_t)src*Do + lane*NC, f);
        #pragma unroll
        for (int c2 = 0; c2 < NC; ++c2) acc[c2] += w_*f[c2];
      }
    }
  }

  float* op = out + (size_t)v*Do + lane*NC;
  const float* bp = bias + lane*NC;
  #pragma unroll
  for (int c2 = 0; c2 < NC; ++c2) op[c2] = reluf(acc[c2] + bp[c2]);
}

// ================= policy final layer =================
__global__ void policy_final_kernel(const float* __restrict__ p3, const float* __restrict__ w,
                                    const float* __restrict__ b, float* __restrict__ out, int n){
  int v = blockIdx.x*256 + threadIdx.x;
  if (v >= n) return;
  float acc = b[0];
  const float4* row = (const float4*)(p3 + (size_t)v*32);
  #pragma unroll
  for (int q = 0; q < 8; ++q){
    float4 x = row[q];
    acc += x.x*w[q*4+0] + x.y*w[q*4+1] + x.z*w[q*4+2] + x.w*w[q*4+3];
  }
  out[v] = acc;
}

// ================= graph boundaries =================
__global__ void bounds_kernel(const int* __restrict__ batch, int* __restrict__ gstart,
                              int n, int G){
  int g = threadIdx.x;
  if (g > G) return;
  int lo = 0, hi = n;
  while (lo < hi){ int mid = (lo + hi) >> 1; if (batch[mid] < g) lo = mid + 1; else hi = mid; }
  gstart[g] = lo;
}

// ================= global add pool: 2-stage split reduction =================
__global__ __launch_bounds__(128) void pool_split_kernel(const float* __restrict__ x,
    const int* __restrict__ gstart, float* __restrict__ partial){
  int g = blockIdx.x, sp = blockIdx.y, f = threadIdx.x;
  int beg = gstart[g], end = gstart[g+1];
  int len = end - beg;
  int chunk = (len + POOL_SPLIT - 1) / POOL_SPLIT;
  int lo = beg + sp*chunk;
  int hi = min(lo + chunk, end);
  float acc = 0.f;
  for (int r = lo; r < hi; ++r) acc += x[(size_t)r*128 + f];
  partial[((size_t)g*POOL_SPLIT + sp)*128 + f] = acc;
}
__global__ __launch_bounds__(128) void pool_final_kernel(const float* __restrict__ partial,
    float* __restrict__ pooled){
  int g = blockIdx.x, f = threadIdx.x;
  float acc = 0.f;
  #pragma unroll
  for (int sp = 0; sp < POOL_SPLIT; ++sp)
    acc += partial[((size_t)g*POOL_SPLIT + sp)*128 + f];
  pooled[g*128 + f] = acc;
}

// ================= value MLP =================
__global__ __launch_bounds__(128) void value_mlp_kernel(const float* __restrict__ pooled,
    const float* __restrict__ W0, const float* __restrict__ B0,
    const float* __restrict__ W1, const float* __restrict__ B1,
    const float* __restrict__ W2, const float* __restrict__ B2,
    const float* __restrict__ W3, const float* __restrict__ B3,
    float* __restrict__ outv){
  __shared__ float a[128], b[128];
  int g = blockIdx.x, t = threadIdx.x;
  a[t] = pooled[g*128 + t];
  __syncthreads();
  float acc = B0[t];
  for (int k = 0; k < 128; ++k) acc += a[k]*W0[k*128 + t];
  b[t] = reluf(acc);
  __syncthreads();
  if (t < 64){ acc = B1[t]; for (int k = 0; k < 128; ++k) acc += b[k]*W1[k*64 + t]; a[t] = reluf(acc); }
  __syncthreads();
  if (t < 32){ acc = B2[t]; for (int k = 0; k < 64; ++k) acc += a[k]*W2[k*32 + t]; b[t] = reluf(acc); }
  __syncthreads();
  if (t == 0){ acc = B3[0]; for (int k = 0; k < 32; ++k) acc += b[k]*W3[k]; outv[g] = acc; }
}

extern "C" void kernel_launch(void* const* d_in, const int* in_sizes, int n_in,
                              void* d_out, int out_size, void* d_ws, size_t ws_size,
                              hipStream_t stream){
  const float* x     = (const float*)d_in[0];
  const int*   ei    = (const int*)d_in[1];
  const int*   batch = (const int*)d_in[2];
  const float* W1 = (const float*)d_in[3];
  const float* as1= (const float*)d_in[4];
  const float* ad1= (const float*)d_in[5];
  const float* b1 = (const float*)d_in[6];
  const float* W2 = (const float*)d_in[7];
  const float* as2= (const float*)d_in[8];
  const float* ad2= (const float*)d_in[9];
  const float* b2 = (const float*)d_in[10];
  const float* W3 = (const float*)d_in[11];
  const float* as3= (const float*)d_in[12];
  const float* ad3= (const float*)d_in[13];
  const float* b3 = (const float*)d_in[14];
  const float* pW0= (const float*)d_in[15];
  const float* pb0= (const float*)d_in[16];
  const float* pW1= (const float*)d_in[17];
  const float* pb1= (const float*)d_in[18];
  const float* pW2= (const float*)d_in[19];
  const float* pb2= (const float*)d_in[20];
  const float* pW3= (const float*)d_in[21];
  const float* pb3= (const float*)d_in[22];
  const float* vW0= (const float*)d_in[23];
  const float* vb0= (const float*)d_in[24];
  const float* vW1= (const float*)d_in[25];
  const float* vb1= (const float*)d_in[26];
  const float* vW2= (const float*)d_in[27];
  const float* vb2= (const float*)d_in[28];
  const float* vW3= (const float*)d_in[29];
  const float* vb3= (const float*)d_in[30];
  float* out = (float*)d_out;

  // -------- workspace carve --------
  char* ws = (char*)d_ws;
  size_t off = 0;
  auto carve = [&](size_t bytes)->char*{
    char* p = ws + off; off = (off + bytes + 255) & ~(size_t)255; return p;
  };
  int*   deg    = (int*)  carve((size_t)N_NODES*4);
  int*   rowptr = (int*)  carve((size_t)(N_NODES+1)*4);
  int*   pos    = (int*)  carve((size_t)N_EDGES*4);
  int*   csr    = (int*)  carve((size_t)N_EDGES*4);
  int*   bsum   = (int*)  carve(512*4);
  float* ew     = (float*)carve((size_t)N_EDGES*4);
  float* s      = (float*)carve((size_t)N_NODES*4);
  float* dsc    = (float*)carve((size_t)N_NODES*4);
  float* wa_s   = (float*)carve(256*4);
  float* wa_d   = (float*)carve(256*4);
  int*   gstart = (int*)  carve(65*4);
  float* pooled = (float*)carve((size_t)N_GRAPHS*128*4);
  float* partial= (float*)carve((size_t)N_GRAPHS*POOL_SPLIT*128*4);
  unsigned short* hbuf = (unsigned short*)carve((size_t)N_NODES*256*2); // bf16 h (all layers)
  float* buf_a  = (float*)carve((size_t)N_NODES*256*4);  // out1; later out3
  float* buf_b  = (float*)carve((size_t)N_NODES*128*4);  // out2; later p1
  // p2/p3 reuse hbuf's storage after layer-3 h is consumed
  float* p2 = (float*)hbuf;                              // [N,64]
  float* p3 = (float*)(hbuf + (size_t)N_NODES*64*2);     // [N,32]

  const int* esrc = ei;              // edge_index[0]
  const int* edst = ei + N_EDGES;    // edge_index[1]

  const int NBn = (N_NODES + 255)/256;   // 391
  const int NBe = (N_EDGES + 255)/256;

  // -------- CSR build --------
  zero_deg_kernel<<<NBn, 256, 0, stream>>>(deg, N_NODES);
  count_kernel<<<NBe, 256, 0, stream>>>(edst, deg, pos, N_EDGES);
  scan1_kernel<<<NBn, 256, 0, stream>>>(deg, rowptr, bsum, N_NODES);
  scan2_kernel<<<1, 512, 0, stream>>>(bsum, NBn);
  scan3_kernel<<<NBn, 256, 0, stream>>>(rowptr, bsum, N_NODES);
  scatter_kernel<<<NBe, 256, 0, stream>>>(esrc, edst, rowptr, pos, csr, N_EDGES);
  bounds_kernel<<<1, 128, 0, stream>>>(batch, gstart, N_NODES, N_GRAPHS);

  const int GB  = (N_NODES + 63) / 64;   // 1563
  const int NB4 = (N_NODES + 3) / 4;

  // ---- layer 1: x[N,59] -> h(bf16)[N,256] -> out1 buf_a(f32)
  wa_kernel<<<1, 256, 0, stream>>>(W1, as1, ad1, wa_s, wa_d, 59, 256);
  gemm_mfma<1><<<dim3(GB,4), 256, 0, stream>>>(x, W1, nullptr, hbuf, N_NODES, 59, 256, 0);
  sd_kernel<<<NB4, 256, 0, stream>>>(x, wa_s, wa_d, s, dsc, N_NODES, 59);
  agg_csr_kernel<4><<<NB4, 256, 0, stream>>>(hbuf, s, dsc, rowptr, deg, csr, ew, b1, buf_a, N_NODES);

  // ---- layer 2: buf_a[N,256] -> h(bf16)[N,128] -> out2 buf_b
  wa_kernel<<<1, 256, 0, stream>>>(W2, as2, ad2, wa_s, wa_d, 256, 128);
  gemm_mfma<1><<<dim3(GB,2), 256, 0, stream>>>(buf_a, W2, nullptr, hbuf, N_NODES, 256, 128, 0);
  sd_kernel<<<NB4, 256, 0, stream>>>(buf_a, wa_s, wa_d, s, dsc, N_NODES, 256);
  agg_csr_kernel<2><<<NB4, 256, 0, stream>>>(hbuf, s, dsc, rowptr, deg, csr, ew, b2, buf_b, N_NODES);

  // ---- layer 3: buf_b[N,128] -> h(bf16)[N,128] -> out3 buf_a
  wa_kernel<<<1, 256, 0, stream>>>(W3, as3, ad3, wa_s, wa_d, 128, 128);
  gemm_mfma<1><<<dim3(GB,2), 256, 0, stream>>>(buf_b, W3, nullptr, hbuf, N_NODES, 128, 128, 0);
  sd_kernel<<<NB4, 256, 0, stream>>>(buf_b, wa_s, wa_d, s, dsc, N_NODES, 128);
  agg_csr_kernel<2><<<NB4, 256, 0, stream>>>(hbuf, s, dsc, rowptr, deg, csr, ew, b3, buf_a, N_NODES);

  // ---- policy MLP: out3(buf_a) -> p1(buf_b) -> p2 -> p3 -> out[0..N)
  gemm_mfma<0><<<dim3(GB,2), 256, 0, stream>>>(buf_a, pW0, pb0, buf_b, N_NODES, 128, 128, 1);
  gemm_mfma<0><<<dim3(GB,1), 256, 0, stream>>>(buf_b, pW1, pb1, p2, N_NODES, 128, 64, 1);
  gemm_kernel<0><<<dim3(GB,1), 256, 0, stream>>>(p2, pW2, pb2, p3, N_NODES, 64, 32, 1);
  policy_final_kernel<<<NBn, 256, 0, stream>>>(p3, pW3, pb3, out, N_NODES);

  // ---- pool + value MLP -> out[N..N+64)
  pool_split_kernel<<<dim3(N_GRAPHS, POOL_SPLIT), 128, 0, stream>>>(buf_a, gstart, partial);
  pool_final_kernel<<<N_GRAPHS, 128, 0, stream>>>(partial, pooled);
  value_mlp_kernel<<<N_GRAPHS, 128, 0, stream>>>(pooled, vW0, vb0, vW1, vb1, vW2, vb2, vW3, vb3,
                                                 out + N_NODES);
}

// Round 7
// 681.650 us; speedup vs baseline: 2.2015x; 1.0776x over previous
//
#include <hip/hip_runtime.h>
#include <hip/hip_bf16.h>
#include <cstdint>

#define N_NODES 100000
#define N_EDGES 800000
#define N_GRAPHS 64
#define POOL_SPLIT 16

typedef short short8 __attribute__((ext_vector_type(8)));
typedef float f32x4 __attribute__((ext_vector_type(4)));

__device__ __forceinline__ float leakyf(float x){ return x >= 0.0f ? x : 0.2f*x; }
__device__ __forceinline__ float reluf(float x){ return x > 0.0f ? x : 0.0f; }

__device__ __forceinline__ float bf2f(unsigned short u){
  union { uint32_t i; float f; } c; c.i = ((uint32_t)u) << 16; return c.f;
}
__device__ __forceinline__ unsigned short f2bf(float x){
  union { float f; uint32_t i; } c; c.f = x;
  uint32_t r = c.i + 0x7FFFu + ((c.i >> 16) & 1u);   // round-to-nearest-even
  return (unsigned short)(r >> 16);
}

// ================= CSR build =================
__global__ void zero_deg_kernel(int* __restrict__ deg, int n){
  int v = blockIdx.x*256 + threadIdx.x;
  if (v < n) deg[v] = 0;
}
__global__ void count_kernel(const int* __restrict__ dst, int* __restrict__ deg,
                             int* __restrict__ pos, int E){
  int e = blockIdx.x*256 + threadIdx.x;
  if (e < E) pos[e] = atomicAdd(&deg[dst[e]], 1);
}
__global__ __launch_bounds__(256) void scan1_kernel(const int* __restrict__ deg,
    int* __restrict__ rowptr, int* __restrict__ bsum, int n){
  __shared__ int sm[256];
  int t = threadIdx.x, i = blockIdx.x*256 + t;
  int v = (i < n) ? deg[i] : 0;
  sm[t] = v; __syncthreads();
  for (int off = 1; off < 256; off <<= 1){
    int x = (t >= off) ? sm[t-off] : 0;
    __syncthreads();
    sm[t] += x;
    __syncthreads();
  }
  if (i < n) rowptr[i] = sm[t] - v;
  if (t == 255) bsum[blockIdx.x] = sm[255];
}
__global__ __launch_bounds__(512) void scan2_kernel(int* __restrict__ bsum, int nb){
  __shared__ int sm[512];
  int t = threadIdx.x;
  int v = (t < nb) ? bsum[t] : 0;
  sm[t] = v; __syncthreads();
  for (int off = 1; off < 512; off <<= 1){
    int x = (t >= off) ? sm[t-off] : 0;
    __syncthreads();
    sm[t] += x;
    __syncthreads();
  }
  if (t < nb) bsum[t] = sm[t] - v;
}
__global__ void scan3_kernel(int* __restrict__ rowptr, const int* __restrict__ bsum, int n){
  int i = blockIdx.x*256 + threadIdx.x;
  if (i < n) rowptr[i] += bsum[blockIdx.x];
}
__global__ void scatter_kernel(const int* __restrict__ src, const int* __restrict__ dst,
                               const int* __restrict__ rowptr, const int* __restrict__ pos,
                               int* __restrict__ csr, int E){
  int e = blockIdx.x*256 + threadIdx.x;
  if (e < E) csr[rowptr[dst[e]] + pos[e]] = src[e];
}

// ================= Wa = W @ a (tiny) =================
__global__ void wa_kernel(const float* __restrict__ W, const float* __restrict__ a_src,
                          const float* __restrict__ a_dst, float* __restrict__ wa_s,
                          float* __restrict__ wa_d, int K, int Do){
  int k = blockIdx.x*blockDim.x + threadIdx.x;
  if (k >= K) return;
  float ss = 0.f, dd = 0.f;
  const float* wr = W + (size_t)k*Do;
  for (int o = 0; o < Do; ++o){ float w = wr[o]; ss += w*a_src[o]; dd += w*a_dst[o]; }
  wa_s[k] = ss; wa_d[k] = dd;
}

// ================= per-node scores (f32 input) =================
__global__ __launch_bounds__(256) void sd_kernel(const float* __restrict__ in,
    const float* __restrict__ wa_s, const float* __restrict__ wa_d,
    float* __restrict__ s, float* __restrict__ d, int n, int K){
  int wid = threadIdx.x >> 6, lane = threadIdx.x & 63;
  int v = (blockIdx.x << 2) + wid;
  if (v >= n) return;
  float ss = 0.f, dd = 0.f;
  const float* row = in + (size_t)v*K;
  for (int k = lane; k < K; k += 64){ float x = row[k]; ss += x*wa_s[k]; dd += x*wa_d[k]; }
  for (int off = 32; off; off >>= 1){ ss += __shfl_down(ss, off); dd += __shfl_down(dd, off); }
  if (lane == 0){ s[v] = ss; d[v] = dd; }
}

// ================= per-node scores (bf16 input, K even) =================
__global__ __launch_bounds__(256) void sd_bf16_kernel(const unsigned short* __restrict__ in,
    const float* __restrict__ wa_s, const float* __restrict__ wa_d,
    float* __restrict__ s, float* __restrict__ d, int n, int K){
  int wid = threadIdx.x >> 6, lane = threadIdx.x & 63;
  int v = (blockIdx.x << 2) + wid;
  if (v >= n) return;
  float ss = 0.f, dd = 0.f;
  const unsigned short* row = in + (size_t)v*K;
  for (int k = lane*2; k < K; k += 128){
    uint32_t u = *(const uint32_t*)&row[k];
    float x0 = bf2f((unsigned short)(u & 0xFFFFu));
    float x1 = bf2f((unsigned short)(u >> 16));
    ss += x0*wa_s[k] + x1*wa_s[k+1];
    dd += x0*wa_d[k] + x1*wa_d[k+1];
  }
  for (int off = 32; off; off >>= 1){ ss += __shfl_down(ss, off); dd += __shfl_down(dd, off); }
  if (lane == 0){ s[v] = ss; d[v] = dd; }
}

// ================= MFMA bf16 GEMM: C = A[MxK] @ W[KxN] (+bias)(+relu) =================
// 64x64 tile, BK=32, 4 waves 2x2, each wave 32x32 (2x2 16x16x32 fragments).
// N%64==0. A f32 (ABF=0, converted at staging) or bf16 (ABF=1, direct short8).
// W is f32 [Kw x N]; rows gk>=Kw read as 0 (A must be zero there too).
template<int ABF, int OBF>
__global__ __launch_bounds__(256) void gemm_mfma(
    const void* __restrict__ Av, const float* __restrict__ W,
    const float* __restrict__ bias, void* __restrict__ Cv,
    int M, int K, int Kw, int N, int act){
  __shared__ short As[64][40];   // [m][k], stride 40 shorts: 2-way conflicts only (free)
  __shared__ short Bs[64][40];   // [n][k]
  const int t = threadIdx.x;
  const int row0 = blockIdx.x * 64;
  const int col0 = blockIdx.y * 64;
  const int wv = t >> 6, lane = t & 63;
  const int wr = wv >> 1, wc = wv & 1;
  const int lr = lane & 15, lg = lane >> 4;

  f32x4 acc00 = {}, acc01 = {}, acc10 = {}, acc11 = {};

  for (int k0 = 0; k0 < K; k0 += 32){
    // ---- stage A: thread t -> row m=t>>2, k-eighth kq=(t&3)*8
    {
      int m = t >> 2, kq = (t & 3) * 8;
      int gr = row0 + m;
      short8 av;
      if constexpr (ABF == 1){
        const unsigned short* Au = (const unsigned short*)Av;
        if (gr < M && (k0 + kq + 7) < K){
          av = *(const short8*)&Au[(size_t)gr*K + k0 + kq];
        } else {
          #pragma unroll
          for (int j = 0; j < 8; ++j){
            int gk = k0 + kq + j;
            av[j] = (gr < M && gk < K) ? (short)Au[(size_t)gr*K + gk] : (short)0;
          }
        }
      } else {
        const float* Af = (const float*)Av;
        if (gr < M && (K % 4) == 0 && (k0 + kq + 7) < K){
          const float4 f0 = *(const float4*)&Af[(size_t)gr*K + k0 + kq];
          const float4 f1 = *(const float4*)&Af[(size_t)gr*K + k0 + kq + 4];
          av[0]=f2bf(f0.x); av[1]=f2bf(f0.y); av[2]=f2bf(f0.z); av[3]=f2bf(f0.w);
          av[4]=f2bf(f1.x); av[5]=f2bf(f1.y); av[6]=f2bf(f1.z); av[7]=f2bf(f1.w);
        } else {
          #pragma unroll
          for (int j = 0; j < 8; ++j){
            int gk = k0 + kq + j;
            float val = (gr < M && gk < K) ? Af[(size_t)gr*K + gk] : 0.f;
            av[j] = f2bf(val);
          }
        }
      }
      *(short8*)&As[m][kq] = av;
    }
    // ---- stage B (transposed): thread t -> col n=t&63, k-eighth k8=(t>>6)*8
    {
      int n = t & 63, k8 = (t >> 6) * 8;
      short8 bv;
      #pragma unroll
      for (int j = 0; j < 8; ++j){
        int gk = k0 + k8 + j;
        float val = (gk < Kw) ? W[(size_t)gk*N + col0 + n] : 0.f;
        bv[j] = f2bf(val);
      }
      *(short8*)&Bs[n][k8] = bv;
    }
    __syncthreads();
    short8 af0 = *(short8*)&As[wr*32 +  0 + lr][lg*8];
    short8 af1 = *(short8*)&As[wr*32 + 16 + lr][lg*8];
    short8 bf0 = *(short8*)&Bs[wc*32 +  0 + lr][lg*8];
    short8 bf1 = *(short8*)&Bs[wc*32 + 16 + lr][lg*8];
    acc00 = __builtin_amdgcn_mfma_f32_16x16x32_bf16(af0, bf0, acc00, 0, 0, 0);
    acc01 = __builtin_amdgcn_mfma_f32_16x16x32_bf16(af0, bf1, acc01, 0, 0, 0);
    acc10 = __builtin_amdgcn_mfma_f32_16x16x32_bf16(af1, bf0, acc10, 0, 0, 0);
    acc11 = __builtin_amdgcn_mfma_f32_16x16x32_bf16(af1, bf1, acc11, 0, 0, 0);
    __syncthreads();
  }

  // ---- C write: lane l, reg j -> row=(l>>4)*4+j, col=l&15
  #pragma unroll
  for (int fm = 0; fm < 2; ++fm){
    #pragma unroll
    for (int fn = 0; fn < 2; ++fn){
      const f32x4 a = (fm==0) ? (fn==0 ? acc00 : acc01) : (fn==0 ? acc10 : acc11);
      int col = col0 + wc*32 + fn*16 + lr;
      float bv = bias ? bias[col] : 0.f;
      #pragma unroll
      for (int j = 0; j < 4; ++j){
        int row = row0 + wr*32 + fm*16 + lg*4 + j;
        if (row >= M) continue;
        float val = a[j] + bv;
        if (act) val = reluf(val);
        if constexpr (OBF == 0) ((float*)Cv)[(size_t)row*N + col] = val;
        else ((unsigned short*)Cv)[(size_t)row*N + col] = f2bf(val);
      }
    }
  }
}

// ================= f32 GEMM (kept for tiny N=32 layer) =================
template<int OBF>
__global__ __launch_bounds__(256) void gemm_kernel(
    const float* __restrict__ A, const float* __restrict__ W,
    const float* __restrict__ bias, void* __restrict__ Cv,
    int M, int K, int N, int act){
  __shared__ float Asf[16][68];
  __shared__ float Wsf[16][64];
  const int t  = threadIdx.x;
  const int tn = t & 15, tm = t >> 4;
  const int row0 = blockIdx.x * 64;
  const int col0 = blockIdx.y * 64;
  float acc[4][4] = {};
  for (int k0 = 0; k0 < K; k0 += 16){
    #pragma unroll
    for (int i = 0; i < 4; ++i){
      int idx = t + i*256;
      int m = idx >> 4, k = idx & 15;
      int r = row0 + m, kk = k0 + k;
      float val = 0.f;
      if (r < M && kk < K) val = A[(size_t)r*K + kk];
      Asf[k][m] = val;
    }
    {
      int k = t >> 4, n4 = (t & 15) * 4;
      int kk = k0 + k, c = col0 + n4;
      float4 wv = make_float4(0.f,0.f,0.f,0.f);
      if (kk < K && c + 3 < N) wv = *(const float4*)&W[(size_t)kk*N + c];
      *(float4*)&Wsf[k][n4] = wv;
    }
    __syncthreads();
    #pragma unroll
    for (int kk = 0; kk < 16; ++kk){
      const float4 a = *(const float4*)&Asf[kk][tm*4];
      const float4 w = *(const float4*)&Wsf[kk][tn*4];
      acc[0][0] += a.x*w.x; acc[0][1] += a.x*w.y; acc[0][2] += a.x*w.z; acc[0][3] += a.x*w.w;
      acc[1][0] += a.y*w.x; acc[1][1] += a.y*w.y; acc[1][2] += a.y*w.z; acc[1][3] += a.y*w.w;
      acc[2][0] += a.z*w.x; acc[2][1] += a.z*w.y; acc[2][2] += a.z*w.z; acc[2][3] += a.z*w.w;
      acc[3][0] += a.w*w.x; acc[3][1] += a.w*w.y; acc[3][2] += a.w*w.z; acc[3][3] += a.w*w.w;
    }
    __syncthreads();
  }
  const int c = col0 + tn*4;
  if (c >= N) return;
  #pragma unroll
  for (int i = 0; i < 4; ++i){
    int r = row0 + tm*4 + i;
    if (r >= M) continue;
    float vals[4];
    #pragma unroll
    for (int j = 0; j < 4; ++j){
      float val = acc[i][j];
      if (bias) val += bias[c + j];
      if (act) val = reluf(val);
      vals[j] = val;
    }
    if constexpr (OBF == 0){
      float* C = (float*)Cv;
      *(float4*)&C[(size_t)r*N + c] = make_float4(vals[0], vals[1], vals[2], vals[3]);
    } else {
      unsigned short* C = (unsigned short*)Cv;
      *(ushort4*)&C[(size_t)r*N + c] =
        make_ushort4(f2bf(vals[0]), f2bf(vals[1]), f2bf(vals[2]), f2bf(vals[3]));
    }
  }
}

// ================= layer-1 pre-aggregation over raw x (f32, 59 cols -> 64 padded) =================
__global__ __launch_bounds__(256) void agg_x_kernel(
    const float* __restrict__ x, const float* __restrict__ s,
    const float* __restrict__ dsc, const int* __restrict__ rowptr,
    const int* __restrict__ deg, const int* __restrict__ csr, float* __restrict__ ew,
    float* __restrict__ outp, int n){
  int wid = threadIdx.x >> 6, lane = threadIdx.x & 63;
  int v = (blockIdx.x << 2) + wid;
  if (v >= n) return;
  const int beg = rowptr[v], dg = deg[v];
  const float dv = dsc[v];
  const float e0 = leakyf(s[v] + dv);
  const bool ok = lane < 59;
  float acc = 0.f;

  if (dg <= 64){
    int srcl = 0; float sc = -1e30f;
    if (lane < dg){ srcl = csr[beg + lane]; sc = leakyf(s[srcl] + dv); }
    float mm = sc;
    #pragma unroll
    for (int off = 32; off; off >>= 1) mm = fmaxf(mm, __shfl_xor(mm, off));
    const float m = fmaxf(e0, mm);
    float w = (lane < dg) ? __expf(sc - m) : 0.f;
    float den = w;
    #pragma unroll
    for (int off = 32; off; off >>= 1) den += __shfl_xor(den, off);
    const float ws0 = __expf(e0 - m);
    den += ws0;
    const float inv = 1.0f / (den + 1e-16f);
    const float wl = w * inv;
    acc = (ws0 * inv) * (ok ? x[(size_t)v*59 + lane] : 0.f);
    int j = 0;
    for (; j + 4 <= dg; j += 4){
      int  s0 = __shfl(srcl, j),   s1 = __shfl(srcl, j+1);
      int  s2 = __shfl(srcl, j+2), s3 = __shfl(srcl, j+3);
      float w0_ = __shfl(wl, j),   w1_ = __shfl(wl, j+1);
      float w2_ = __shfl(wl, j+2), w3_ = __shfl(wl, j+3);
      float f0 = ok ? x[(size_t)s0*59 + lane] : 0.f;
      float f1 = ok ? x[(size_t)s1*59 + lane] : 0.f;
      float f2 = ok ? x[(size_t)s2*59 + lane] : 0.f;
      float f3 = ok ? x[(size_t)s3*59 + lane] : 0.f;
      acc += w0_*f0 + w1_*f1 + w2_*f2 + w3_*f3;
    }
    for (; j < dg; ++j){
      int src = __shfl(srcl, j);
      float w_ = __shfl(wl, j);
      acc += w_ * (ok ? x[(size_t)src*59 + lane] : 0.f);
    }
  } else {
    float m = e0;
    for (int base = 0; base < dg; base += 64){
      int i = base + lane; float sc = -1e30f;
      if (i < dg){ int src = csr[beg + i]; sc = leakyf(s[src] + dv); ew[beg + i] = sc; }
      #pragma unroll
      for (int off = 32; off; off >>= 1) sc = fmaxf(sc, __shfl_xor(sc, off));
      m = fmaxf(m, sc);
    }
    float dsum = 0.f;
    for (int base = 0; base < dg; base += 64){
      int i = base + lane; float w = 0.f;
      if (i < dg){ w = __expf(ew[beg + i] - m); ew[beg + i] = w; }
      float cs = w;
      #pragma unroll
      for (int off = 32; off; off >>= 1) cs += __shfl_xor(cs, off);
      dsum += cs;
    }
    const float ws0 = __expf(e0 - m);
    const float inv = 1.0f / (dsum + ws0 + 1e-16f);
    acc = (ws0 * inv) * (ok ? x[(size_t)v*59 + lane] : 0.f);
    for (int base = 0; base < dg; base += 64){
      int i = base + lane;
      int srcl = 0; float wl = 0.f;
      if (i < dg){ srcl = csr[beg + i]; wl = ew[beg + i] * inv; }
      int cnt = min(64, dg - base);
      for (int j = 0; j < cnt; ++j){
        int src = __shfl(srcl, j);
        float w_ = __shfl(wl, j);
        acc += w_ * (ok ? x[(size_t)src*59 + lane] : 0.f);
      }
    }
  }
  outp[(size_t)v*64 + lane] = ok ? acc : 0.f;   // padded cols 59..63 = 0
}

// ================= CSR edge-softmax aggregation, h in bf16 =================
template<int NC>
__device__ __forceinline__ void load_row(const unsigned short* p, float* f){
  if constexpr (NC == 2){
    uint32_t u = *(const uint32_t*)p;
    union { uint32_t i; float ff; } a, b;
    a.i = u << 16; b.i = u & 0xFFFF0000u;
    f[0] = a.ff; f[1] = b.ff;
  } else {
    uint2 u = *(const uint2*)p;
    union { uint32_t i; float ff; } a, b, c, d;
    a.i = u.x << 16; b.i = u.x & 0xFFFF0000u;
    c.i = u.y << 16; d.i = u.y & 0xFFFF0000u;
    f[0] = a.ff; f[1] = b.ff; f[2] = c.ff; f[3] = d.ff;
  }
}

template<int NC>   // Do = NC*64
__global__ __launch_bounds__(256) void agg_csr_kernel(
    const unsigned short* __restrict__ h, const float* __restrict__ s,
    const float* __restrict__ dsc, const int* __restrict__ rowptr,
    const int* __restrict__ deg, const int* __restrict__ csr, float* __restrict__ ew,
    const float* __restrict__ bias, float* __restrict__ out, int n){
  const int Do = NC*64;
  int wid = threadIdx.x >> 6, lane = threadIdx.x & 63;
  int v = (blockIdx.x << 2) + wid;
  if (v >= n) return;
  const int beg = rowptr[v];
  const int dg  = deg[v];
  const float dv = dsc[v];
  const float e0 = leakyf(s[v] + dv);
  float acc[NC];

  if (dg <= 64){
    int srcl = 0; float sc = -1e30f;
    if (lane < dg){ srcl = csr[beg + lane]; sc = leakyf(s[srcl] + dv); }
    float mm = sc;
    #pragma unroll
    for (int off = 32; off; off >>= 1) mm = fmaxf(mm, __shfl_xor(mm, off));
    const float m = fmaxf(e0, mm);
    float w = (lane < dg) ? __expf(sc - m) : 0.f;
    float den = w;
    #pragma unroll
    for (int off = 32; off; off >>= 1) den += __shfl_xor(den, off);
    const float ws0 = __expf(e0 - m);
    den += ws0;
    const float inv = 1.0f / (den + 1e-16f);
    const float wl = w * inv;
    {
      const float w0 = ws0 * inv;
      const unsigned short* hp = h + (size_t)v*Do + lane*NC;
      float f[NC]; load_row<NC>(hp, f);
      #pragma unroll
      for (int c2 = 0; c2 < NC; ++c2) acc[c2] = w0 * f[c2];
    }
    int j = 0;
    for (; j + 4 <= dg; j += 4){
      int  s0 = __shfl(srcl, j),   s1 = __shfl(srcl, j+1);
      int  s2 = __shfl(srcl, j+2), s3 = __shfl(srcl, j+3);
      float w0_ = __shfl(wl, j),   w1_ = __shfl(wl, j+1);
      float w2_ = __shfl(wl, j+2), w3_ = __shfl(wl, j+3);
      float f0[NC], f1[NC], f2[NC], f3[NC];
      load_row<NC>(h + (size_t)s0*Do + lane*NC, f0);
      load_row<NC>(h + (size_t)s1*Do + lane*NC, f1);
      load_row<NC>(h + (size_t)s2*Do + lane*NC, f2);
      load_row<NC>(h + (size_t)s3*Do + lane*NC, f3);
      #pragma unroll
      for (int c2 = 0; c2 < NC; ++c2)
        acc[c2] += w0_*f0[c2] + w1_*f1[c2] + w2_*f2[c2] + w3_*f3[c2];
    }
    for (; j < dg; ++j){
      int src = __shfl(srcl, j);
      float w_ = __shfl(wl, j);
      float f[NC]; load_row<NC>(h + (size_t)src*Do + lane*NC, f);
      #pragma unroll
      for (int c2 = 0; c2 < NC; ++c2) acc[c2] += w_*f[c2];
    }
  } else {
    float m = e0;
    for (int base = 0; base < dg; base += 64){
      int i = base + lane; float sc = -1e30f;
      if (i < dg){ int src = csr[beg + i]; sc = leakyf(s[src] + dv); ew[beg + i] = sc; }
      #pragma unroll
      for (int off = 32; off; off >>= 1) sc = fmaxf(sc, __shfl_xor(sc, off));
      m = fmaxf(m, sc);
    }
    float dsum = 0.f;
    for (int base = 0; base < dg; base += 64){
      int i = base + lane; float w = 0.f;
      if (i < dg){ w = __expf(ew[beg + i] - m); ew[beg + i] = w; }
      float cs = w;
      #pragma unroll
      for (int off = 32; off; off >>= 1) cs += __shfl_xor(cs, off);
      dsum += cs;
    }
    const float ws0 = __expf(e0 - m);
    const float inv = 1.0f / (dsum + ws0 + 1e-16f);
    {
      const float w0 = ws0 * inv;
      float f[NC]; load_row<NC>(h + (size_t)v*Do + lane*NC, f);
      #pragma unroll
      for (int c2 = 0; c2 < NC; ++c2) acc[c2] = w0 * f[c2];
    }
    for (int base = 0; base < dg; base += 64){
      int i = base + lane;
      int srcl = 0; float wl = 0.f;
      if (i < dg){ srcl = csr[beg + i]; wl = ew[beg + i] * inv; }
      int cnt = min(64, dg - base);
      for (int j = 0; j < cnt; ++j){
        int src = __shfl(srcl, j);
        float w_ = __shfl(wl, j);
        float f[NC]; load_row<NC>(h + (size_t)src*Do + lane*NC, f);
        #pragma unroll
        for (int c2 = 0; c2 < NC; ++c2) acc[c2] += w_*f[c2];
      }
    }
  }

  float* op = out + (size_t)v*Do + lane*NC;
  const float* bp = bias + lane*NC;
  #pragma unroll
  for (int c2 = 0; c2 < NC; ++c2) op[c2] = reluf(acc[c2] + bp[c2]);
}

// ================= policy final layer =================
__global__ void policy_final_kernel(const float* __restrict__ p3, const float* __restrict__ w,
                                    const float* __restrict__ b, float* __restrict__ out, int n){
  int v = blockIdx.x*256 + threadIdx.x;
  if (v >= n) return;
  float acc = b[0];
  const float4* row = (const float4*)(p3 + (size_t)v*32);
  #pragma unroll
  for (int q = 0; q < 8; ++q){
    float4 x = row[q];
    acc += x.x*w[q*4+0] + x.y*w[q*4+1] + x.z*w[q*4+2] + x.w*w[q*4+3];
  }
  out[v] = acc;
}

// ================= graph boundaries =================
__global__ void bounds_kernel(const int* __restrict__ batch, int* __restrict__ gstart,
                              int n, int G){
  int g = threadIdx.x;
  if (g > G) return;
  int lo = 0, hi = n;
  while (lo < hi){ int mid = (lo + hi) >> 1; if (batch[mid] < g) lo = mid + 1; else hi = mid; }
  gstart[g] = lo;
}

// ================= global add pool: 2-stage split reduction =================
__global__ __launch_bounds__(128) void pool_split_kernel(const float* __restrict__ x,
    const int* __restrict__ gstart, float* __restrict__ partial){
  int g = blockIdx.x, sp = blockIdx.y, f = threadIdx.x;
  int beg = gstart[g], end = gstart[g+1];
  int len = end - beg;
  int chunk = (len + POOL_SPLIT - 1) / POOL_SPLIT;
  int lo = beg + sp*chunk;
  int hi = min(lo + chunk, end);
  float acc = 0.f;
  for (int r = lo; r < hi; ++r) acc += x[(size_t)r*128 + f];
  partial[((size_t)g*POOL_SPLIT + sp)*128 + f] = acc;
}
__global__ __launch_bounds__(128) void pool_final_kernel(const float* __restrict__ partial,
    float* __restrict__ pooled){
  int g = blockIdx.x, f = threadIdx.x;
  float acc = 0.f;
  #pragma unroll
  for (int sp = 0; sp < POOL_SPLIT; ++sp)
    acc += partial[((size_t)g*POOL_SPLIT + sp)*128 + f];
  pooled[g*128 + f] = acc;
}

// ================= value MLP =================
__global__ __launch_bounds__(128) void value_mlp_kernel(const float* __restrict__ pooled,
    const float* __restrict__ W0, const float* __restrict__ B0,
    const float* __restrict__ W1, const float* __restrict__ B1,
    const float* __restrict__ W2, const float* __restrict__ B2,
    const float* __restrict__ W3, const float* __restrict__ B3,
    float* __restrict__ outv){
  __shared__ float a[128], b[128];
  int g = blockIdx.x, t = threadIdx.x;
  a[t] = pooled[g*128 + t];
  __syncthreads();
  float acc = B0[t];
  for (int k = 0; k < 128; ++k) acc += a[k]*W0[k*128 + t];
  b[t] = reluf(acc);
  __syncthreads();
  if (t < 64){ acc = B1[t]; for (int k = 0; k < 128; ++k) acc += b[k]*W1[k*64 + t]; a[t] = reluf(acc); }
  __syncthreads();
  if (t < 32){ acc = B2[t]; for (int k = 0; k < 64; ++k) acc += a[k]*W2[k*32 + t]; b[t] = reluf(acc); }
  __syncthreads();
  if (t == 0){ acc = B3[0]; for (int k = 0; k < 32; ++k) acc += b[k]*W3[k]; outv[g] = acc; }
}

extern "C" void kernel_launch(void* const* d_in, const int* in_sizes, int n_in,
                              void* d_out, int out_size, void* d_ws, size_t ws_size,
                              hipStream_t stream){
  const float* x     = (const float*)d_in[0];
  const int*   ei    = (const int*)d_in[1];
  const int*   batch = (const int*)d_in[2];
  const float* W1 = (const float*)d_in[3];
  const float* as1= (const float*)d_in[4];
  const float* ad1= (const float*)d_in[5];
  const float* b1 = (const float*)d_in[6];
  const float* W2 = (const float*)d_in[7];
  const float* as2= (const float*)d_in[8];
  const float* ad2= (const float*)d_in[9];
  const float* b2 = (const float*)d_in[10];
  const float* W3 = (const float*)d_in[11];
  const float* as3= (const float*)d_in[12];
  const float* ad3= (const float*)d_in[13];
  const float* b3 = (const float*)d_in[14];
  const float* pW0= (const float*)d_in[15];
  const float* pb0= (const float*)d_in[16];
  const float* pW1= (const float*)d_in[17];
  const float* pb1= (const float*)d_in[18];
  const float* pW2= (const float*)d_in[19];
  const float* pb2= (const float*)d_in[20];
  const float* pW3= (const float*)d_in[21];
  const float* pb3= (const float*)d_in[22];
  const float* vW0= (const float*)d_in[23];
  const float* vb0= (const float*)d_in[24];
  const float* vW1= (const float*)d_in[25];
  const float* vb1= (const float*)d_in[26];
  const float* vW2= (const float*)d_in[27];
  const float* vb2= (const float*)d_in[28];
  const float* vW3= (const float*)d_in[29];
  const float* vb3= (const float*)d_in[30];
  float* out = (float*)d_out;

  // -------- workspace carve (~220 MB) --------
  char* ws = (char*)d_ws;
  size_t off = 0;
  auto carve = [&](size_t bytes)->char*{
    char* p = ws + off; off = (off + bytes + 255) & ~(size_t)255; return p;
  };
  int*   deg    = (int*)  carve((size_t)N_NODES*4);
  int*   rowptr = (int*)  carve((size_t)(N_NODES+1)*4);
  int*   pos    = (int*)  carve((size_t)N_EDGES*4);
  int*   csr    = (int*)  carve((size_t)N_EDGES*4);
  int*   bsum   = (int*)  carve(512*4);
  float* ew     = (float*)carve((size_t)N_EDGES*4);
  float* s      = (float*)carve((size_t)N_NODES*4);
  float* dsc    = (float*)carve((size_t)N_NODES*4);
  float* wa_s   = (float*)carve(256*4);
  float* wa_d   = (float*)carve(256*4);
  int*   gstart = (int*)  carve(65*4);
  float* pooled = (float*)carve((size_t)N_GRAPHS*128*4);
  float* partial= (float*)carve((size_t)N_GRAPHS*POOL_SPLIT*128*4);
  float* aggx   = (float*)carve((size_t)N_NODES*64*4);          // agg'd x, padded to 64 (25.6MB)
  unsigned short* obuf1 = (unsigned short*)carve((size_t)N_NODES*256*2); // out1 bf16 (51.2MB)
  unsigned short* hbuf  = (unsigned short*)carve((size_t)N_NODES*128*2); // h2/h3 bf16 (25.6MB)
  float* buf_b  = (float*)carve((size_t)N_NODES*128*4);         // out2 f32 (51.2MB)
  float* buf_a  = (float*)carve((size_t)N_NODES*128*4);         // out3 f32 (51.2MB, live to end)
  // reuse dead regions for policy MLP intermediates
  float* p1 = (float*)obuf1;   // [N,128] f32 (51.2MB) — obuf1 dead after gemm h2
  float* p2 = aggx;            // [N,64]  f32 (25.6MB) — aggx dead after gemm L1
  float* p3 = buf_b;           // [N,32]  f32          — buf_b dead after gemm h3

  const int* esrc = ei;              // edge_index[0]
  const int* edst = ei + N_EDGES;    // edge_index[1]

  const int NBn = (N_NODES + 255)/256;
  const int NBe = (N_EDGES + 255)/256;

  // -------- CSR build --------
  zero_deg_kernel<<<NBn, 256, 0, stream>>>(deg, N_NODES);
  count_kernel<<<NBe, 256, 0, stream>>>(edst, deg, pos, N_EDGES);
  scan1_kernel<<<NBn, 256, 0, stream>>>(deg, rowptr, bsum, N_NODES);
  scan2_kernel<<<1, 512, 0, stream>>>(bsum, NBn);
  scan3_kernel<<<NBn, 256, 0, stream>>>(rowptr, bsum, N_NODES);
  scatter_kernel<<<NBe, 256, 0, stream>>>(esrc, edst, rowptr, pos, csr, N_EDGES);
  bounds_kernel<<<1, 128, 0, stream>>>(batch, gstart, N_NODES, N_GRAPHS);

  const int GB  = (N_NODES + 63) / 64;   // 1563
  const int NB4 = (N_NODES + 3) / 4;

  // ---- layer 1 (pre-aggregated): sd(x) -> agg_x -> GEMM(aggx@W1 + b1, relu) -> out1 bf16
  wa_kernel<<<1, 256, 0, stream>>>(W1, as1, ad1, wa_s, wa_d, 59, 256);
  sd_kernel<<<NB4, 256, 0, stream>>>(x, wa_s, wa_d, s, dsc, N_NODES, 59);
  agg_x_kernel<<<NB4, 256, 0, stream>>>(x, s, dsc, rowptr, deg, csr, ew, aggx, N_NODES);
  gemm_mfma<0,1><<<dim3(GB,4), 256, 0, stream>>>(aggx, W1, b1, obuf1, N_NODES, 64, 59, 256, 1);

  // ---- layer 2: out1(bf16)[N,256] -> h2(bf16)[N,128] -> out2 buf_b(f32)
  wa_kernel<<<1, 256, 0, stream>>>(W2, as2, ad2, wa_s, wa_d, 256, 128);
  sd_bf16_kernel<<<NB4, 256, 0, stream>>>(obuf1, wa_s, wa_d, s, dsc, N_NODES, 256);
  gemm_mfma<1,1><<<dim3(GB,2), 256, 0, stream>>>(obuf1, W2, nullptr, hbuf, N_NODES, 256, 256, 128, 0);
  agg_csr_kernel<2><<<NB4, 256, 0, stream>>>(hbuf, s, dsc, rowptr, deg, csr, ew, b2, buf_b, N_NODES);

  // ---- layer 3: out2(f32)[N,128] -> h3(bf16)[N,128] -> out3 buf_a(f32)
  wa_kernel<<<1, 256, 0, stream>>>(W3, as3, ad3, wa_s, wa_d, 128, 128);
  sd_kernel<<<NB4, 256, 0, stream>>>(buf_b, wa_s, wa_d, s, dsc, N_NODES, 128);
  gemm_mfma<0,1><<<dim3(GB,2), 256, 0, stream>>>(buf_b, W3, nullptr, hbuf, N_NODES, 128, 128, 128, 0);
  agg_csr_kernel<2><<<NB4, 256, 0, stream>>>(hbuf, s, dsc, rowptr, deg, csr, ew, b3, buf_a, N_NODES);

  // ---- policy MLP: out3(buf_a) -> p1 -> p2 -> p3 -> out[0..N)
  gemm_mfma<0,0><<<dim3(GB,2), 256, 0, stream>>>(buf_a, pW0, pb0, p1, N_NODES, 128, 128, 128, 1);
  gemm_mfma<0,0><<<dim3(GB,1), 256, 0, stream>>>(p1, pW1, pb1, p2, N_NODES, 128, 128, 64, 1);
  gemm_kernel<0><<<dim3(GB,1), 256, 0, stream>>>(p2, pW2, pb2, p3, N_NODES, 64, 32, 1);
  policy_final_kernel<<<NBn, 256, 0, stream>>>(p3, pW3, pb3, out, N_NODES);

  // ---- pool + value MLP -> out[N..N+64)
  pool_split_kernel<<<dim3(N_GRAPHS, POOL_SPLIT), 128, 0, stream>>>(buf_a, gstart, partial);
  pool_final_kernel<<<N_GRAPHS, 128, 0, stream>>>(partial, pooled);
  value_mlp_kernel<<<N_GRAPHS, 128, 0, stream>>>(pooled, vW0, vb0, vW1, vb1, vW2, vb2, vW3, vb3,
                                                 out + N_NODES);
}

// Round 11
// 575.042 us; speedup vs baseline: 2.6096x; 1.1854x over previous
//
#include <hip/hip_runtime.h>
#include <hip/hip_bf16.h>
#include <cstdint>

#define N_NODES 100000
#define N_EDGES 800000
#define N_GRAPHS 64
#define POOL_SPLIT 16

typedef short short8 __attribute__((ext_vector_type(8)));
typedef float f32x4 __attribute__((ext_vector_type(4)));

__device__ __forceinline__ float leakyf(float x){ return x >= 0.0f ? x : 0.2f*x; }
__device__ __forceinline__ float reluf(float x){ return x > 0.0f ? x : 0.0f; }

__device__ __forceinline__ float bf2f(unsigned short u){
  union { uint32_t i; float f; } c; c.i = ((uint32_t)u) << 16; return c.f;
}
__device__ __forceinline__ unsigned short f2bf(float x){
  union { float f; uint32_t i; } c; c.f = x;
  uint32_t r = c.i + 0x7FFFu + ((c.i >> 16) & 1u);   // RNE
  return (unsigned short)(r >> 16);
}
__device__ __forceinline__ uint32_t pack2(float a, float b){
  return (uint32_t)f2bf(a) | ((uint32_t)f2bf(b) << 16);
}

// ================= x -> bf16 padded [N,64] =================
__global__ __launch_bounds__(256) void x2bf_kernel(const float* __restrict__ x,
    uint32_t* __restrict__ xb, int n){
  int idx = blockIdx.x*256 + threadIdx.x;       // over n*32 uints
  if (idx >= n*32) return;
  int v = idx >> 5, c2 = (idx & 31)*2;
  float f0 = (c2   < 59) ? x[(size_t)v*59 + c2]     : 0.f;
  float f1 = (c2+1 < 59) ? x[(size_t)v*59 + c2 + 1] : 0.f;
  xb[idx] = pack2(f0, f1);
}

// ================= CSR build =================
__global__ void zero_deg_kernel(int* __restrict__ deg, int n){
  int v = blockIdx.x*256 + threadIdx.x;
  if (v < n) deg[v] = 0;
}
__global__ void count_kernel(const int* __restrict__ dst, int* __restrict__ deg,
                             int* __restrict__ pos, int E){
  int e = blockIdx.x*256 + threadIdx.x;
  if (e < E) pos[e] = atomicAdd(&deg[dst[e]], 1);
}
__global__ __launch_bounds__(256) void scan1_kernel(const int* __restrict__ deg,
    int* __restrict__ rowptr, int* __restrict__ bsum, int n){
  __shared__ int sm[256];
  int t = threadIdx.x, i = blockIdx.x*256 + t;
  int v = (i < n) ? deg[i] : 0;
  sm[t] = v; __syncthreads();
  for (int off = 1; off < 256; off <<= 1){
    int x = (t >= off) ? sm[t-off] : 0;
    __syncthreads();
    sm[t] += x;
    __syncthreads();
  }
  if (i < n) rowptr[i] = sm[t] - v;
  if (t == 255) bsum[blockIdx.x] = sm[255];
}
__global__ __launch_bounds__(512) void scan2_kernel(int* __restrict__ bsum, int nb){
  __shared__ int sm[512];
  int t = threadIdx.x;
  int v = (t < nb) ? bsum[t] : 0;
  sm[t] = v; __syncthreads();
  for (int off = 1; off < 512; off <<= 1){
    int x = (t >= off) ? sm[t-off] : 0;
    __syncthreads();
    sm[t] += x;
    __syncthreads();
  }
  if (t < nb) bsum[t] = sm[t] - v;
}
__global__ void scan3_kernel(int* __restrict__ rowptr, const int* __restrict__ bsum, int n){
  int i = blockIdx.x*256 + threadIdx.x;
  if (i < n) rowptr[i] += bsum[blockIdx.x];
}
__global__ void scatter_kernel(const int* __restrict__ src, const int* __restrict__ dst,
                               const int* __restrict__ rowptr, const int* __restrict__ pos,
                               int* __restrict__ csr, int E){
  int e = blockIdx.x*256 + threadIdx.x;
  if (e < E) csr[rowptr[dst[e]] + pos[e]] = src[e];
}

// ================= all Wa = W @ a in one launch =================
// wa layout: [0:64) s1 | [64:128) d1 | [128:384) s2 | [384:640) d2 | [640:768) s3 | [768:896) d3
__global__ __launch_bounds__(256) void wa_all_kernel(
    const float* __restrict__ W1, const float* __restrict__ as1, const float* __restrict__ ad1,
    const float* __restrict__ W2, const float* __restrict__ as2, const float* __restrict__ ad2,
    const float* __restrict__ W3, const float* __restrict__ as3, const float* __restrict__ ad3,
    float* __restrict__ wa){
  int t = threadIdx.x;
  { float ss=0.f, dd=0.f; const float* wr = W2 + (size_t)t*128;
    for (int o=0;o<128;++o){ float w=wr[o]; ss+=w*as2[o]; dd+=w*ad2[o]; }
    wa[128+t]=ss; wa[384+t]=dd; }
  if (t < 128){ float ss=0.f, dd=0.f; const float* wr = W3 + (size_t)t*128;
    for (int o=0;o<128;++o){ float w=wr[o]; ss+=w*as3[o]; dd+=w*ad3[o]; }
    wa[640+t]=ss; wa[768+t]=dd; }
  if (t < 64){ float ss=0.f, dd=0.f;
    if (t < 59){ const float* wr = W1 + (size_t)t*256;
      for (int o=0;o<256;++o){ float w=wr[o]; ss+=w*as1[o]; dd+=w*ad1[o]; } }
    wa[t]=ss; wa[64+t]=dd; }
}

// ================= per-node scores (bf16 input, K even) =================
__global__ __launch_bounds__(256) void sd_bf16_kernel(const unsigned short* __restrict__ in,
    const float* __restrict__ wa_s, const float* __restrict__ wa_d,
    float* __restrict__ s, float* __restrict__ d, int n, int K){
  int wid = threadIdx.x >> 6, lane = threadIdx.x & 63;
  int v = (blockIdx.x << 2) + wid;
  if (v >= n) return;
  float ss = 0.f, dd = 0.f;
  const unsigned short* row = in + (size_t)v*K;
  for (int k = lane*2; k < K; k += 128){
    uint32_t u = *(const uint32_t*)&row[k];
    float x0 = bf2f((unsigned short)(u & 0xFFFFu));
    float x1 = bf2f((unsigned short)(u >> 16));
    ss += x0*wa_s[k] + x1*wa_s[k+1];
    dd += x0*wa_d[k] + x1*wa_d[k+1];
  }
  for (int off = 32; off; off >>= 1){ ss += __shfl_down(ss, off); dd += __shfl_down(dd, off); }
  if (lane == 0){ s[v] = ss; d[v] = dd; }
}

// ================= unified half-wave edge-softmax aggregation (bf16 in/out) =================
template<int NC>
__device__ __forceinline__ void gload(const unsigned short* rowp, int hl, float* f){
  if constexpr (NC == 1){
    uint32_t u = ((const uint32_t*)rowp)[hl];
    f[0] = bf2f((unsigned short)(u & 0xFFFFu));
    f[1] = bf2f((unsigned short)(u >> 16));
  } else {
    uint2 u = ((const uint2*)rowp)[hl];
    f[0] = bf2f((unsigned short)(u.x & 0xFFFFu));
    f[1] = bf2f((unsigned short)(u.x >> 16));
    f[2] = bf2f((unsigned short)(u.y & 0xFFFFu));
    f[3] = bf2f((unsigned short)(u.y >> 16));
  }
}

// NC: uints per lane (1 -> C=64 cols, 2 -> C=128 cols). BR: 1 = bias+relu epilogue.
// 8 nodes per 256-thread block; each half-wave (32 lanes) owns one dst node.
template<int NC, int BR>
__global__ __launch_bounds__(256) void agg_half(
    const unsigned short* __restrict__ hb, const float* __restrict__ s,
    const float* __restrict__ dsc, const int* __restrict__ rowptr,
    const int* __restrict__ deg, const int* __restrict__ csr, float* __restrict__ ew,
    const float* __restrict__ bias, unsigned short* __restrict__ outp, int n){
  const int C = NC*64;
  const int tid = threadIdx.x;
  const int hl   = tid & 31;        // lane within half-wave
  const int base = tid & 32;        // absolute wave-lane offset of this half-wave
  const int v = blockIdx.x*8 + (tid >> 5);
  if (v >= n) return;
  const int beg = rowptr[v], dg = deg[v];
  const float dv = dsc[v];
  const float e0 = leakyf(s[v] + dv);
  float acc[2*NC];

  if (dg <= 32){
    int srcl = 0; float sc = -1e30f;
    if (hl < dg){ srcl = csr[beg + hl]; sc = leakyf(s[srcl] + dv); }
    float mm = sc;
    #pragma unroll
    for (int off = 16; off; off >>= 1) mm = fmaxf(mm, __shfl_xor(mm, off));
    const float m = fmaxf(e0, mm);
    float w = (hl < dg) ? __expf(sc - m) : 0.f;
    float den = w;
    #pragma unroll
    for (int off = 16; off; off >>= 1) den += __shfl_xor(den, off);
    const float ws0 = __expf(e0 - m);
    const float inv = 1.0f / (den + ws0 + 1e-16f);
    const float wl = w * inv;
    {
      float f[2*NC]; gload<NC>(hb + (size_t)v*C, hl, f);
      const float w0 = ws0 * inv;
      #pragma unroll
      for (int c = 0; c < 2*NC; ++c) acc[c] = w0 * f[c];
    }
    int j = 0;
    for (; j + 4 <= dg; j += 4){
      int  s0 = __shfl(srcl, base+j),   s1 = __shfl(srcl, base+j+1);
      int  s2 = __shfl(srcl, base+j+2), s3 = __shfl(srcl, base+j+3);
      float w0_ = __shfl(wl, base+j),   w1_ = __shfl(wl, base+j+1);
      float w2_ = __shfl(wl, base+j+2), w3_ = __shfl(wl, base+j+3);
      float f0[2*NC], f1[2*NC], f2[2*NC], f3[2*NC];
      gload<NC>(hb + (size_t)s0*C, hl, f0);
      gload<NC>(hb + (size_t)s1*C, hl, f1);
      gload<NC>(hb + (size_t)s2*C, hl, f2);
      gload<NC>(hb + (size_t)s3*C, hl, f3);
      #pragma unroll
      for (int c = 0; c < 2*NC; ++c)
        acc[c] += w0_*f0[c] + w1_*f1[c] + w2_*f2[c] + w3_*f3[c];
    }
    for (; j < dg; ++j){
      int src = __shfl(srcl, base+j);
      float w_ = __shfl(wl, base+j);
      float f[2*NC]; gload<NC>(hb + (size_t)src*C, hl, f);
      #pragma unroll
      for (int c = 0; c < 2*NC; ++c) acc[c] += w_*f[c];
    }
  } else {
    // chunked path (rare): spill scores to ew
    float m = e0;
    for (int b0 = 0; b0 < dg; b0 += 32){
      int i = b0 + hl; float sc = -1e30f;
      if (i < dg){ int src = csr[beg + i]; sc = leakyf(s[src] + dv); ew[beg + i] = sc; }
      #pragma unroll
      for (int off = 16; off; off >>= 1) sc = fmaxf(sc, __shfl_xor(sc, off));
      m = fmaxf(m, sc);
    }
    float dsum = 0.f;
    for (int b0 = 0; b0 < dg; b0 += 32){
      int i = b0 + hl; float w = 0.f;
      if (i < dg){ w = __expf(ew[beg + i] - m); ew[beg + i] = w; }
      float cs = w;
      #pragma unroll
      for (int off = 16; off; off >>= 1) cs += __shfl_xor(cs, off);
      dsum += cs;
    }
    const float ws0 = __expf(e0 - m);
    const float inv = 1.0f / (dsum + ws0 + 1e-16f);
    {
      float f[2*NC]; gload<NC>(hb + (size_t)v*C, hl, f);
      const float w0 = ws0 * inv;
      #pragma unroll
      for (int c = 0; c < 2*NC; ++c) acc[c] = w0 * f[c];
    }
    for (int b0 = 0; b0 < dg; b0 += 32){
      int i = b0 + hl;
      int srcl = 0; float wl = 0.f;
      if (i < dg){ srcl = csr[beg + i]; wl = ew[beg + i] * inv; }
      int cnt = min(32, dg - b0);
      for (int j = 0; j < cnt; ++j){
        int src = __shfl(srcl, base+j);
        float w_ = __shfl(wl, base+j);
        float f[2*NC]; gload<NC>(hb + (size_t)src*C, hl, f);
        #pragma unroll
        for (int c = 0; c < 2*NC; ++c) acc[c] += w_*f[c];
      }
    }
  }

  unsigned short* op = outp + (size_t)v*C;
  if constexpr (NC == 1){
    float v0 = acc[0], v1 = acc[1];
    if constexpr (BR){ v0 = reluf(v0 + bias[2*hl]); v1 = reluf(v1 + bias[2*hl+1]); }
    ((uint32_t*)op)[hl] = pack2(v0, v1);
  } else {
    float v0=acc[0], v1=acc[1], v2=acc[2], v3=acc[3];
    if constexpr (BR){
      v0 = reluf(v0 + bias[4*hl]);   v1 = reluf(v1 + bias[4*hl+1]);
      v2 = reluf(v2 + bias[4*hl+2]); v3 = reluf(v3 + bias[4*hl+3]);
    }
    uint2 u; u.x = pack2(v0, v1); u.y = pack2(v2, v3);
    ((uint2*)op)[hl] = u;
  }
}

// ================= MFMA bf16 GEMM: C = A[MxK] @ W[KxN] (+bias)(+relu) =================
// 64x64 tile, BK=32, 4 waves 2x2. N%64==0. A f32 (ABF=0) or bf16 (ABF=1).
// W f32 [Kw x N]; rows gk>=Kw read as 0 (A zero-padded there).
template<int ABF, int OBF>
__global__ __launch_bounds__(256) void gemm_mfma(
    const void* __restrict__ Av, const float* __restrict__ W,
    const float* __restrict__ bias, void* __restrict__ Cv,
    int M, int K, int Kw, int N, int act){
  __shared__ short As[64][40];
  __shared__ short Bs[64][40];
  const int t = threadIdx.x;
  const int row0 = blockIdx.x * 64;
  const int col0 = blockIdx.y * 64;
  const int wv = t >> 6, lane = t & 63;
  const int wr = wv >> 1, wc = wv & 1;
  const int lr = lane & 15, lg = lane >> 4;

  f32x4 acc00 = {}, acc01 = {}, acc10 = {}, acc11 = {};

  for (int k0 = 0; k0 < K; k0 += 32){
    {
      int m = t >> 2, kq = (t & 3) * 8;
      int gr = row0 + m;
      short8 av;
      if constexpr (ABF == 1){
        const unsigned short* Au = (const unsigned short*)Av;
        if (gr < M && (k0 + kq + 7) < K){
          av = *(const short8*)&Au[(size_t)gr*K + k0 + kq];
        } else {
          #pragma unroll
          for (int j = 0; j < 8; ++j){
            int gk = k0 + kq + j;
            av[j] = (gr < M && gk < K) ? (short)Au[(size_t)gr*K + gk] : (short)0;
          }
        }
      } else {
        const float* Af = (const float*)Av;
        if (gr < M && (K % 4) == 0 && (k0 + kq + 7) < K){
          const float4 f0 = *(const float4*)&Af[(size_t)gr*K + k0 + kq];
          const float4 f1 = *(const float4*)&Af[(size_t)gr*K + k0 + kq + 4];
          av[0]=f2bf(f0.x); av[1]=f2bf(f0.y); av[2]=f2bf(f0.z); av[3]=f2bf(f0.w);
          av[4]=f2bf(f1.x); av[5]=f2bf(f1.y); av[6]=f2bf(f1.z); av[7]=f2bf(f1.w);
        } else {
          #pragma unroll
          for (int j = 0; j < 8; ++j){
            int gk = k0 + kq + j;
            float val = (gr < M && gk < K) ? Af[(size_t)gr*K + gk] : 0.f;
            av[j] = f2bf(val);
          }
        }
      }
      *(short8*)&As[m][kq] = av;
    }
    {
      int n = t & 63, k8 = (t >> 6) * 8;
      short8 bv;
      #pragma unroll
      for (int j = 0; j < 8; ++j){
        int gk = k0 + k8 + j;
        float val = (gk < Kw) ? W[(size_t)gk*N + col0 + n] : 0.f;
        bv[j] = f2bf(val);
      }
      *(short8*)&Bs[n][k8] = bv;
    }
    __syncthreads();
    short8 af0 = *(short8*)&As[wr*32 +  0 + lr][lg*8];
    short8 af1 = *(short8*)&As[wr*32 + 16 + lr][lg*8];
    short8 bf0 = *(short8*)&Bs[wc*32 +  0 + lr][lg*8];
    short8 bf1 = *(short8*)&Bs[wc*32 + 16 + lr][lg*8];
    acc00 = __builtin_amdgcn_mfma_f32_16x16x32_bf16(af0, bf0, acc00, 0, 0, 0);
    acc01 = __builtin_amdgcn_mfma_f32_16x16x32_bf16(af0, bf1, acc01, 0, 0, 0);
    acc10 = __builtin_amdgcn_mfma_f32_16x16x32_bf16(af1, bf0, acc10, 0, 0, 0);
    acc11 = __builtin_amdgcn_mfma_f32_16x16x32_bf16(af1, bf1, acc11, 0, 0, 0);
    __syncthreads();
  }

  #pragma unroll
  for (int fm = 0; fm < 2; ++fm){
    #pragma unroll
    for (int fn = 0; fn < 2; ++fn){
      const f32x4 a = (fm==0) ? (fn==0 ? acc00 : acc01) : (fn==0 ? acc10 : acc11);
      int col = col0 + wc*32 + fn*16 + lr;
      float bv = bias ? bias[col] : 0.f;
      #pragma unroll
      for (int j = 0; j < 4; ++j){
        int row = row0 + wr*32 + fm*16 + lg*4 + j;
        if (row >= M) continue;
        float val = a[j] + bv;
        if (act) val = reluf(val);
        if constexpr (OBF == 0) ((float*)Cv)[(size_t)row*N + col] = val;
        else ((unsigned short*)Cv)[(size_t)row*N + col] = f2bf(val);
      }
    }
  }
}

// ================= fused policy tail: p2[N,64] -> relu(p2@W2+b2) @ w3 + b3 =================
__global__ __launch_bounds__(256) void policy_tail_kernel(
    const float* __restrict__ p2, const float* __restrict__ W2, const float* __restrict__ B2,
    const float* __restrict__ W3, const float* __restrict__ B3,
    float* __restrict__ out, int n){
  __shared__ float w2[64*32];
  __shared__ float w3[32];
  __shared__ float b2s[32];
  int t = threadIdx.x;
  for (int i = t; i < 2048; i += 256) w2[i] = W2[i];
  if (t < 32){ w3[t] = W3[t]; b2s[t] = B2[t]; }
  __syncthreads();
  int v = blockIdx.x*256 + t;
  if (v >= n) return;
  const float* row = p2 + (size_t)v*64;
  float acc32[32];
  #pragma unroll
  for (int o = 0; o < 32; ++o) acc32[o] = b2s[o];
  for (int k = 0; k < 64; ++k){
    float xk = row[k];
    #pragma unroll
    for (int o = 0; o < 32; ++o) acc32[o] += xk * w2[k*32 + o];
  }
  float accf = B3[0];
  #pragma unroll
  for (int o = 0; o < 32; ++o) accf += reluf(acc32[o]) * w3[o];
  out[v] = accf;
}

// ================= graph boundaries =================
__global__ void bounds_kernel(const int* __restrict__ batch, int* __restrict__ gstart,
                              int n, int G){
  int g = threadIdx.x;
  if (g > G) return;
  int lo = 0, hi = n;
  while (lo < hi){ int mid = (lo + hi) >> 1; if (batch[mid] < g) lo = mid + 1; else hi = mid; }
  gstart[g] = lo;
}

// ================= global add pool: 2-stage split reduction =================
__global__ __launch_bounds__(128) void pool_split_kernel(const float* __restrict__ x,
    const int* __restrict__ gstart, float* __restrict__ partial){
  int g = blockIdx.x, sp = blockIdx.y, f = threadIdx.x;
  int beg = gstart[g], end = gstart[g+1];
  int len = end - beg;
  int chunk = (len + POOL_SPLIT - 1) / POOL_SPLIT;
  int lo = beg + sp*chunk;
  int hi = min(lo + chunk, end);
  float acc = 0.f;
  for (int r = lo; r < hi; ++r) acc += x[(size_t)r*128 + f];
  partial[((size_t)g*POOL_SPLIT + sp)*128 + f] = acc;
}
__global__ __launch_bounds__(128) void pool_final_kernel(const float* __restrict__ partial,
    float* __restrict__ pooled){
  int g = blockIdx.x, f = threadIdx.x;
  float acc = 0.f;
  #pragma unroll
  for (int sp = 0; sp < POOL_SPLIT; ++sp)
    acc += partial[((size_t)g*POOL_SPLIT + sp)*128 + f];
  pooled[g*128 + f] = acc;
}

// ================= value MLP =================
__global__ __launch_bounds__(128) void value_mlp_kernel(const float* __restrict__ pooled,
    const float* __restrict__ W0, const float* __restrict__ B0,
    const float* __restrict__ W1, const float* __restrict__ B1,
    const float* __restrict__ W2, const float* __restrict__ B2,
    const float* __restrict__ W3, const float* __restrict__ B3,
    float* __restrict__ outv){
  __shared__ float a[128], b[128];
  int g = blockIdx.x, t = threadIdx.x;
  a[t] = pooled[g*128 + t];
  __syncthreads();
  float acc = B0[t];
  for (int k = 0; k < 128; ++k) acc += a[k]*W0[k*128 + t];
  b[t] = reluf(acc);
  __syncthreads();
  if (t < 64){ acc = B1[t]; for (int k = 0; k < 128; ++k) acc += b[k]*W1[k*64 + t]; a[t] = reluf(acc); }
  __syncthreads();
  if (t < 32){ acc = B2[t]; for (int k = 0; k < 64; ++k) acc += a[k]*W2[k*32 + t]; b[t] = reluf(acc); }
  __syncthreads();
  if (t == 0){ acc = B3[0]; for (int k = 0; k < 32; ++k) acc += b[k]*W3[k]; outv[g] = acc; }
}

extern "C" void kernel_launch(void* const* d_in, const int* in_sizes, int n_in,
                              void* d_out, int out_size, void* d_ws, size_t ws_size,
                              hipStream_t stream){
  const float* x     = (const float*)d_in[0];
  const int*   ei    = (const int*)d_in[1];
  const int*   batch = (const int*)d_in[2];
  const float* W1 = (const float*)d_in[3];
  const float* as1= (const float*)d_in[4];
  const float* ad1= (const float*)d_in[5];
  const float* b1 = (const float*)d_in[6];
  const float* W2 = (const float*)d_in[7];
  const float* as2= (const float*)d_in[8];
  const float* ad2= (const float*)d_in[9];
  const float* b2 = (const float*)d_in[10];
  const float* W3 = (const float*)d_in[11];
  const float* as3= (const float*)d_in[12];
  const float* ad3= (const float*)d_in[13];
  const float* b3 = (const float*)d_in[14];
  const float* pW0= (const float*)d_in[15];
  const float* pb0= (const float*)d_in[16];
  const float* pW1= (const float*)d_in[17];
  const float* pb1= (const float*)d_in[18];
  const float* pW2= (const float*)d_in[19];
  const float* pb2= (const float*)d_in[20];
  const float* pW3= (const float*)d_in[21];
  const float* pb3= (const float*)d_in[22];
  const float* vW0= (const float*)d_in[23];
  const float* vb0= (const float*)d_in[24];
  const float* vW1= (const float*)d_in[25];
  const float* vb1= (const float*)d_in[26];
  const float* vW2= (const float*)d_in[27];
  const float* vb2= (const float*)d_in[28];
  const float* vW3= (const float*)d_in[29];
  const float* vb3= (const float*)d_in[30];
  float* out = (float*)d_out;

  // -------- workspace carve --------
  char* ws = (char*)d_ws;
  size_t off = 0;
  auto carve = [&](size_t bytes)->char*{
    char* p = ws + off; off = (off + bytes + 255) & ~(size_t)255; return p;
  };
  int*   deg    = (int*)  carve((size_t)N_NODES*4);
  int*   rowptr = (int*)  carve((size_t)(N_NODES+1)*4);
  int*   pos    = (int*)  carve((size_t)N_EDGES*4);
  int*   csr    = (int*)  carve((size_t)N_EDGES*4);
  int*   bsum   = (int*)  carve(512*4);
  float* ew     = (float*)carve((size_t)N_EDGES*4);
  float* s      = (float*)carve((size_t)N_NODES*4);
  float* dsc    = (float*)carve((size_t)N_NODES*4);
  float* wa     = (float*)carve(1024*4);
  int*   gstart = (int*)  carve(65*4);
  float* pooled = (float*)carve((size_t)N_GRAPHS*128*4);
  float* partial= (float*)carve((size_t)N_GRAPHS*POOL_SPLIT*128*4);
  uint32_t*       xb   = (uint32_t*)      carve((size_t)N_NODES*64*2);   // bf16 [N,64] padded
  unsigned short* aggx = (unsigned short*)carve((size_t)N_NODES*64*2);   // bf16 [N,64]
  unsigned short* out1 = (unsigned short*)carve((size_t)N_NODES*256*2);  // bf16 [N,256]
  unsigned short* h2   = (unsigned short*)carve((size_t)N_NODES*128*2);  // bf16 [N,128]
  unsigned short* out2 = (unsigned short*)carve((size_t)N_NODES*128*2);  // bf16 [N,128]
  unsigned short* agg3 = (unsigned short*)carve((size_t)N_NODES*128*2);  // bf16 [N,128]
  float* out3 = (float*)carve((size_t)N_NODES*128*4);                    // f32 [N,128]
  // reuse dead regions for policy MLP intermediates
  unsigned short* p1 = h2;          // bf16 [N,128] — h2 dead after agg2
  float* p2 = (float*)out1;         // f32 [N,64] (25.6MB fits in out1's 51.2MB) — out1 dead after gemm h2

  const int* esrc = ei;              // edge_index[0]
  const int* edst = ei + N_EDGES;    // edge_index[1]

  const int NBn = (N_NODES + 255)/256;
  const int NBe = (N_EDGES + 255)/256;
  const int GB  = (N_NODES + 63) / 64;   // 1563
  const int NB4 = (N_NODES + 3) / 4;
  const int NB8 = (N_NODES + 7) / 8;

  // -------- prep: x->bf16, CSR build, wa, bounds --------
  x2bf_kernel<<<(N_NODES*32 + 255)/256, 256, 0, stream>>>(x, xb, N_NODES);
  zero_deg_kernel<<<NBn, 256, 0, stream>>>(deg, N_NODES);
  count_kernel<<<NBe, 256, 0, stream>>>(edst, deg, pos, N_EDGES);
  scan1_kernel<<<NBn, 256, 0, stream>>>(deg, rowptr, bsum, N_NODES);
  scan2_kernel<<<1, 512, 0, stream>>>(bsum, NBn);
  scan3_kernel<<<NBn, 256, 0, stream>>>(rowptr, bsum, N_NODES);
  scatter_kernel<<<NBe, 256, 0, stream>>>(esrc, edst, rowptr, pos, csr, N_EDGES);
  wa_all_kernel<<<1, 256, 0, stream>>>(W1, as1, ad1, W2, as2, ad2, W3, as3, ad3, wa);
  bounds_kernel<<<1, 128, 0, stream>>>(batch, gstart, N_NODES, N_GRAPHS);

  // ---- layer 1 (pre-agg): sd(xb) -> agg(xb) -> GEMM(+b1,relu) -> out1 bf16
  sd_bf16_kernel<<<NB4, 256, 0, stream>>>((const unsigned short*)xb, wa+0, wa+64, s, dsc, N_NODES, 64);
  agg_half<1,0><<<NB8, 256, 0, stream>>>((const unsigned short*)xb, s, dsc, rowptr, deg, csr, ew,
                                         nullptr, aggx, N_NODES);
  gemm_mfma<1,1><<<dim3(GB,4), 256, 0, stream>>>(aggx, W1, b1, out1, N_NODES, 64, 59, 256, 1);

  // ---- layer 2 (post-agg): sd(out1) -> GEMM -> h2 bf16 -> agg(+b2,relu) -> out2 bf16
  sd_bf16_kernel<<<NB4, 256, 0, stream>>>(out1, wa+128, wa+384, s, dsc, N_NODES, 256);
  gemm_mfma<1,1><<<dim3(GB,2), 256, 0, stream>>>(out1, W2, nullptr, h2, N_NODES, 256, 256, 128, 0);
  agg_half<2,1><<<NB8, 256, 0, stream>>>(h2, s, dsc, rowptr, deg, csr, ew, b2, out2, N_NODES);

  // ---- layer 3 (pre-agg): sd(out2) -> agg(out2) -> GEMM(+b3,relu) -> out3 f32
  sd_bf16_kernel<<<NB4, 256, 0, stream>>>(out2, wa+640, wa+768, s, dsc, N_NODES, 128);
  agg_half<2,0><<<NB8, 256, 0, stream>>>(out2, s, dsc, rowptr, deg, csr, ew, nullptr, agg3, N_NODES);
  gemm_mfma<1,0><<<dim3(GB,2), 256, 0, stream>>>(agg3, W3, b3, out3, N_NODES, 128, 128, 128, 1);

  // ---- policy MLP: out3 -> p1(bf16) -> p2(f32) -> fused tail -> out[0..N)
  gemm_mfma<0,1><<<dim3(GB,2), 256, 0, stream>>>(out3, pW0, pb0, p1, N_NODES, 128, 128, 128, 1);
  gemm_mfma<1,0><<<dim3(GB,1), 256, 0, stream>>>(p1, pW1, pb1, p2, N_NODES, 128, 128, 64, 1);
  policy_tail_kernel<<<NBn, 256, 0, stream>>>(p2, pW2, pb2, pW3, pb3, out, N_NODES);

  // ---- pool + value MLP -> out[N..N+64)
  pool_split_kernel<<<dim3(N_GRAPHS, POOL_SPLIT), 128, 0, stream>>>(out3, gstart, partial);
  pool_final_kernel<<<N_GRAPHS, 128, 0, stream>>>(partial, pooled);
  value_mlp_kernel<<<N_GRAPHS, 128, 0, stream>>>(pooled, vW0, vb0, vW1, vb1, vW2, vb2, vW3, vb3,
                                                 out + N_NODES);
}

// Round 15
// 556.394 us; speedup vs baseline: 2.6971x; 1.0335x over previous
//
#include <hip/hip_runtime.h>
#include <hip/hip_bf16.h>
#include <cstdint>

#define N_NODES 100000
#define N_EDGES 800000
#define N_GRAPHS 64
#define POOL_SPLIT 16

typedef short short8 __attribute__((ext_vector_type(8)));
typedef float f32x4 __attribute__((ext_vector_type(4)));

__device__ __forceinline__ float leakyf(float x){ return x >= 0.0f ? x : 0.2f*x; }
__device__ __forceinline__ float reluf(float x){ return x > 0.0f ? x : 0.0f; }

__device__ __forceinline__ float bf2f(unsigned short u){
  union { uint32_t i; float f; } c; c.i = ((uint32_t)u) << 16; return c.f;
}
__device__ __forceinline__ unsigned short f2bf(float x){
  union { float f; uint32_t i; } c; c.f = x;
  uint32_t r = c.i + 0x7FFFu + ((c.i >> 16) & 1u);   // RNE
  return (unsigned short)(r >> 16);
}
__device__ __forceinline__ uint32_t pack2(float a, float b){
  return (uint32_t)f2bf(a) | ((uint32_t)f2bf(b) << 16);
}

// ================= CSR build =================
__global__ void zero_deg_kernel(int* __restrict__ deg, int n){
  int v = blockIdx.x*256 + threadIdx.x;
  if (v < n) deg[v] = 0;
}
__global__ void count_kernel(const int* __restrict__ dst, int* __restrict__ deg,
                             int* __restrict__ pos, int E){
  int e = blockIdx.x*256 + threadIdx.x;
  if (e < E) pos[e] = atomicAdd(&deg[dst[e]], 1);
}
__global__ __launch_bounds__(256) void scan1_kernel(const int* __restrict__ deg,
    int* __restrict__ rowptr, int* __restrict__ bsum, int n){
  __shared__ int sm[256];
  int t = threadIdx.x, i = blockIdx.x*256 + t;
  int v = (i < n) ? deg[i] : 0;
  sm[t] = v; __syncthreads();
  for (int off = 1; off < 256; off <<= 1){
    int x = (t >= off) ? sm[t-off] : 0;
    __syncthreads();
    sm[t] += x;
    __syncthreads();
  }
  if (i < n) rowptr[i] = sm[t] - v;
  if (t == 255) bsum[blockIdx.x] = sm[255];
}
__global__ __launch_bounds__(512) void scan2_kernel(int* __restrict__ bsum, int nb){
  __shared__ int sm[512];
  int t = threadIdx.x;
  int v = (t < nb) ? bsum[t] : 0;
  sm[t] = v; __syncthreads();
  for (int off = 1; off < 512; off <<= 1){
    int x = (t >= off) ? sm[t-off] : 0;
    __syncthreads();
    sm[t] += x;
    __syncthreads();
  }
  if (t < nb) bsum[t] = sm[t] - v;
}
__global__ void scan3_kernel(int* __restrict__ rowptr, const int* __restrict__ bsum, int n){
  int i = blockIdx.x*256 + threadIdx.x;
  if (i < n) rowptr[i] += bsum[blockIdx.x];
}
__global__ void scatter_kernel(const int* __restrict__ src, const int* __restrict__ dst,
                               const int* __restrict__ rowptr, const int* __restrict__ pos,
                               int* __restrict__ csr, int E){
  int e = blockIdx.x*256 + threadIdx.x;
  if (e < E) csr[rowptr[dst[e]] + pos[e]] = src[e];
}

// ================= all Wa = W @ a in one launch =================
// wa layout: [0:64) s1 | [64:128) d1 | [128:384) s2 | [384:640) d2 | [640:768) s3 | [768:896) d3
__global__ __launch_bounds__(256) void wa_all_kernel(
    const float* __restrict__ W1, const float* __restrict__ as1, const float* __restrict__ ad1,
    const float* __restrict__ W2, const float* __restrict__ as2, const float* __restrict__ ad2,
    const float* __restrict__ W3, const float* __restrict__ as3, const float* __restrict__ ad3,
    float* __restrict__ wa){
  int t = threadIdx.x;
  { float ss=0.f, dd=0.f; const float* wr = W2 + (size_t)t*128;
    for (int o=0;o<128;++o){ float w=wr[o]; ss+=w*as2[o]; dd+=w*ad2[o]; }
    wa[128+t]=ss; wa[384+t]=dd; }
  if (t < 128){ float ss=0.f, dd=0.f; const float* wr = W3 + (size_t)t*128;
    for (int o=0;o<128;++o){ float w=wr[o]; ss+=w*as3[o]; dd+=w*ad3[o]; }
    wa[640+t]=ss; wa[768+t]=dd; }
  if (t < 64){ float ss=0.f, dd=0.f;
    if (t < 59){ const float* wr = W1 + (size_t)t*256;
      for (int o=0;o<256;++o){ float w=wr[o]; ss+=w*as1[o]; dd+=w*ad1[o]; } }
    wa[t]=ss; wa[64+t]=dd; }
}

// ================= x -> bf16 [N,64] + layer-1 scores (fused) =================
// half-wave (32 lanes) per row: lane hl handles cols 2hl, 2hl+1
__global__ __launch_bounds__(256) void x2bf_sd_kernel(const float* __restrict__ x,
    const float* __restrict__ wa_s, const float* __restrict__ wa_d,
    uint32_t* __restrict__ xb, float* __restrict__ s, float* __restrict__ d, int n){
  int hl = threadIdx.x & 31;
  int v = blockIdx.x*8 + (threadIdx.x >> 5);
  if (v >= n) return;
  int c0 = 2*hl, c1 = 2*hl + 1;
  float f0 = (c0 < 59) ? x[(size_t)v*59 + c0] : 0.f;
  float f1 = (c1 < 59) ? x[(size_t)v*59 + c1] : 0.f;
  xb[(size_t)v*32 + hl] = pack2(f0, f1);
  float ss = f0*wa_s[c0] + f1*wa_s[c1];
  float dd = f0*wa_d[c0] + f1*wa_d[c1];
  #pragma unroll
  for (int off = 16; off; off >>= 1){ ss += __shfl_xor(ss, off); dd += __shfl_xor(dd, off); }
  if (hl == 0){ s[v] = ss; d[v] = dd; }
}

// ================= per-node scores (bf16 input, K even) =================
__global__ __launch_bounds__(256) void sd_bf16_kernel(const unsigned short* __restrict__ in,
    const float* __restrict__ wa_s, const float* __restrict__ wa_d,
    float* __restrict__ s, float* __restrict__ d, int n, int K){
  int wid = threadIdx.x >> 6, lane = threadIdx.x & 63;
  int v = (blockIdx.x << 2) + wid;
  if (v >= n) return;
  float ss = 0.f, dd = 0.f;
  const unsigned short* row = in + (size_t)v*K;
  for (int k = lane*2; k < K; k += 128){
    uint32_t u = *(const uint32_t*)&row[k];
    float x0 = bf2f((unsigned short)(u & 0xFFFFu));
    float x1 = bf2f((unsigned short)(u >> 16));
    ss += x0*wa_s[k] + x1*wa_s[k+1];
    dd += x0*wa_d[k] + x1*wa_d[k+1];
  }
  for (int off = 32; off; off >>= 1){ ss += __shfl_down(ss, off); dd += __shfl_down(dd, off); }
  if (lane == 0){ s[v] = ss; d[v] = dd; }
}

// ================= quarter-wave edge-softmax aggregation (bf16 in/out) =================
// NC=1: C=64 cols, lane loads uint2 (4 ch). NC=2: C=128 cols, lane loads uint4 (8 ch).
template<int NC>
__device__ __forceinline__ void qload(const unsigned short* rowp, int ql, float* f){
  if constexpr (NC == 1){
    uint2 u = ((const uint2*)rowp)[ql];
    f[0]=bf2f((unsigned short)(u.x & 0xFFFFu)); f[1]=bf2f((unsigned short)(u.x >> 16));
    f[2]=bf2f((unsigned short)(u.y & 0xFFFFu)); f[3]=bf2f((unsigned short)(u.y >> 16));
  } else {
    uint4 u = ((const uint4*)rowp)[ql];
    f[0]=bf2f((unsigned short)(u.x & 0xFFFFu)); f[1]=bf2f((unsigned short)(u.x >> 16));
    f[2]=bf2f((unsigned short)(u.y & 0xFFFFu)); f[3]=bf2f((unsigned short)(u.y >> 16));
    f[4]=bf2f((unsigned short)(u.z & 0xFFFFu)); f[5]=bf2f((unsigned short)(u.z >> 16));
    f[6]=bf2f((unsigned short)(u.w & 0xFFFFu)); f[7]=bf2f((unsigned short)(u.w >> 16));
  }
}

// BR: bias+relu epilogue. SDF: fuse next-layer score computation (dot with sdw_s/d).
// 16 nodes per 256-thread block; each quarter-wave (16 lanes) owns one dst node.
template<int NC, int BR, int SDF>
__global__ __launch_bounds__(256) void agg_q(
    const unsigned short* __restrict__ hb, const float* __restrict__ s,
    const float* __restrict__ dsc, const int* __restrict__ rowptr,
    const int* __restrict__ deg, const int* __restrict__ csr, float* __restrict__ ew,
    const float* __restrict__ bias,
    const float* __restrict__ sdw_s, const float* __restrict__ sdw_d,
    float* __restrict__ s_out, float* __restrict__ d_out,
    unsigned short* __restrict__ outp, int n){
  const int C  = NC*64;
  const int CH = NC*4;                    // channels per lane
  const int tid  = threadIdx.x;
  const int ql   = tid & 15;
  const int base = (tid & 63) & 48;       // quarter base lane within wave
  const int v = blockIdx.x*16 + (tid >> 4);
  if (v >= n) return;
  const int beg = rowptr[v], dg = deg[v];
  const float dv = dsc[v];
  const float e0 = leakyf(s[v] + dv);
  float acc[CH];

  if (dg <= 16){
    int srcl = 0; float sc = -1e30f;
    if (ql < dg){ srcl = csr[beg + ql]; sc = leakyf(s[srcl] + dv); }
    float mm = sc;
    #pragma unroll
    for (int off = 8; off; off >>= 1) mm = fmaxf(mm, __shfl_xor(mm, off));
    const float m = fmaxf(e0, mm);
    float w = (ql < dg) ? __expf(sc - m) : 0.f;
    float den = w;
    #pragma unroll
    for (int off = 8; off; off >>= 1) den += __shfl_xor(den, off);
    const float ws0 = __expf(e0 - m);
    const float inv = 1.0f / (den + ws0 + 1e-16f);
    const float wl = w * inv;
    {
      float f[CH]; qload<NC>(hb + (size_t)v*C, ql, f);
      const float w0 = ws0 * inv;
      #pragma unroll
      for (int c = 0; c < CH; ++c) acc[c] = w0 * f[c];
    }
    int j = 0;
    for (; j + 4 <= dg; j += 4){
      int  s0 = __shfl(srcl, base+j),   s1 = __shfl(srcl, base+j+1);
      int  s2 = __shfl(srcl, base+j+2), s3 = __shfl(srcl, base+j+3);
      float w0_ = __shfl(wl, base+j),   w1_ = __shfl(wl, base+j+1);
      float w2_ = __shfl(wl, base+j+2), w3_ = __shfl(wl, base+j+3);
      float f0[CH], f1[CH], f2[CH], f3[CH];
      qload<NC>(hb + (size_t)s0*C, ql, f0);
      qload<NC>(hb + (size_t)s1*C, ql, f1);
      qload<NC>(hb + (size_t)s2*C, ql, f2);
      qload<NC>(hb + (size_t)s3*C, ql, f3);
      #pragma unroll
      for (int c = 0; c < CH; ++c)
        acc[c] += w0_*f0[c] + w1_*f1[c] + w2_*f2[c] + w3_*f3[c];
    }
    for (; j < dg; ++j){
      int src = __shfl(srcl, base+j);
      float w_ = __shfl(wl, base+j);
      float f[CH]; qload<NC>(hb + (size_t)src*C, ql, f);
      #pragma unroll
      for (int c = 0; c < CH; ++c) acc[c] += w_*f[c];
    }
  } else {
    // chunked path (dg>16, ~0.4% of nodes): spill scores to ew
    float m = e0;
    for (int b0 = 0; b0 < dg; b0 += 16){
      int i = b0 + ql; float sc = -1e30f;
      if (i < dg){ int src = csr[beg + i]; sc = leakyf(s[src] + dv); ew[beg + i] = sc; }
      #pragma unroll
      for (int off = 8; off; off >>= 1) sc = fmaxf(sc, __shfl_xor(sc, off));
      m = fmaxf(m, sc);
    }
    float dsum = 0.f;
    for (int b0 = 0; b0 < dg; b0 += 16){
      int i = b0 + ql; float w = 0.f;
      if (i < dg){ w = __expf(ew[beg + i] - m); ew[beg + i] = w; }
      float cs = w;
      #pragma unroll
      for (int off = 8; off; off >>= 1) cs += __shfl_xor(cs, off);
      dsum += cs;
    }
    const float ws0 = __expf(e0 - m);
    const float inv = 1.0f / (dsum + ws0 + 1e-16f);
    {
      float f[CH]; qload<NC>(hb + (size_t)v*C, ql, f);
      const float w0 = ws0 * inv;
      #pragma unroll
      for (int c = 0; c < CH; ++c) acc[c] = w0 * f[c];
    }
    for (int b0 = 0; b0 < dg; b0 += 16){
      int i = b0 + ql;
      int srcl = 0; float wl = 0.f;
      if (i < dg){ srcl = csr[beg + i]; wl = ew[beg + i] * inv; }
      int cnt = min(16, dg - b0);
      for (int j = 0; j < cnt; ++j){
        int src = __shfl(srcl, base+j);
        float w_ = __shfl(wl, base+j);
        float f[CH]; qload<NC>(hb + (size_t)src*C, ql, f);
        #pragma unroll
        for (int c = 0; c < CH; ++c) acc[c] += w_*f[c];
      }
    }
  }

  // epilogue: bias+relu (BR), pack+store, fused next-layer scores (SDF)
  float vout[CH];
  #pragma unroll
  for (int c = 0; c < CH; ++c){
    float val = acc[c];
    if constexpr (BR) val = reluf(val + bias[CH*ql + c]);
    vout[c] = val;
  }
  unsigned short* op = outp + (size_t)v*C;
  if constexpr (NC == 1){
    uint2 u; u.x = pack2(vout[0], vout[1]); u.y = pack2(vout[2], vout[3]);
    ((uint2*)op)[ql] = u;
  } else {
    uint4 u;
    u.x = pack2(vout[0], vout[1]); u.y = pack2(vout[2], vout[3]);
    u.z = pack2(vout[4], vout[5]); u.w = pack2(vout[6], vout[7]);
    ((uint4*)op)[ql] = u;
  }
  if constexpr (SDF){
    float ss = 0.f, dd = 0.f;
    #pragma unroll
    for (int c = 0; c < CH; ++c){
      ss += vout[c] * sdw_s[CH*ql + c];
      dd += vout[c] * sdw_d[CH*ql + c];
    }
    #pragma unroll
    for (int off = 8; off; off >>= 1){ ss += __shfl_xor(ss, off); dd += __shfl_xor(dd, off); }
    if (ql == 0){ s_out[v] = ss; d_out[v] = dd; }
  }
}

// ================= MFMA bf16 GEMM: C = A[MxK] @ W[KxN] (+bias)(+relu) =================
// 64x64 tile, BK=32, 4 waves 2x2. N%64==0. A f32 (ABF=0) or bf16 (ABF=1).
// W f32 [Kw x N]; rows gk>=Kw read as 0 (A zero-padded there).
template<int ABF, int OBF>
__global__ __launch_bounds__(256) void gemm_mfma(
    const void* __restrict__ Av, const float* __restrict__ W,
    const float* __restrict__ bias, void* __restrict__ Cv,
    int M, int K, int Kw, int N, int act){
  __shared__ short As[64][40];
  __shared__ short Bs[64][40];
  const int t = threadIdx.x;
  const int row0 = blockIdx.x * 64;
  const int col0 = blockIdx.y * 64;
  const int wv = t >> 6, lane = t & 63;
  const int wr = wv >> 1, wc = wv & 1;
  const int lr = lane & 15, lg = lane >> 4;

  f32x4 acc00 = {}, acc01 = {}, acc10 = {}, acc11 = {};

  for (int k0 = 0; k0 < K; k0 += 32){
    {
      int m = t >> 2, kq = (t & 3) * 8;
      int gr = row0 + m;
      short8 av;
      if constexpr (ABF == 1){
        const unsigned short* Au = (const unsigned short*)Av;
        if (gr < M && (k0 + kq + 7) < K){
          av = *(const short8*)&Au[(size_t)gr*K + k0 + kq];
        } else {
          #pragma unroll
          for (int j = 0; j < 8; ++j){
            int gk = k0 + kq + j;
            av[j] = (gr < M && gk < K) ? (short)Au[(size_t)gr*K + gk] : (short)0;
          }
        }
      } else {
        const float* Af = (const float*)Av;
        if (gr < M && (K % 4) == 0 && (k0 + kq + 7) < K){
          const float4 f0 = *(const float4*)&Af[(size_t)gr*K + k0 + kq];
          const float4 f1 = *(const float4*)&Af[(size_t)gr*K + k0 + kq + 4];
          av[0]=f2bf(f0.x); av[1]=f2bf(f0.y); av[2]=f2bf(f0.z); av[3]=f2bf(f0.w);
          av[4]=f2bf(f1.x); av[5]=f2bf(f1.y); av[6]=f2bf(f1.z); av[7]=f2bf(f1.w);
        } else {
          #pragma unroll
          for (int j = 0; j < 8; ++j){
            int gk = k0 + kq + j;
            float val = (gr < M && gk < K) ? Af[(size_t)gr*K + gk] : 0.f;
            av[j] = f2bf(val);
          }
        }
      }
      *(short8*)&As[m][kq] = av;
    }
    {
      int n = t & 63, k8 = (t >> 6) * 8;
      short8 bv;
      #pragma unroll
      for (int j = 0; j < 8; ++j){
        int gk = k0 + k8 + j;
        float val = (gk < Kw) ? W[(size_t)gk*N + col0 + n] : 0.f;
        bv[j] = f2bf(val);
      }
      *(short8*)&Bs[n][k8] = bv;
    }
    __syncthreads();
    short8 af0 = *(short8*)&As[wr*32 +  0 + lr][lg*8];
    short8 af1 = *(short8*)&As[wr*32 + 16 + lr][lg*8];
    short8 bf0 = *(short8*)&Bs[wc*32 +  0 + lr][lg*8];
    short8 bf1 = *(short8*)&Bs[wc*32 + 16 + lr][lg*8];
    acc00 = __builtin_amdgcn_mfma_f32_16x16x32_bf16(af0, bf0, acc00, 0, 0, 0);
    acc01 = __builtin_amdgcn_mfma_f32_16x16x32_bf16(af0, bf1, acc01, 0, 0, 0);
    acc10 = __builtin_amdgcn_mfma_f32_16x16x32_bf16(af1, bf0, acc10, 0, 0, 0);
    acc11 = __builtin_amdgcn_mfma_f32_16x16x32_bf16(af1, bf1, acc11, 0, 0, 0);
    __syncthreads();
  }

  #pragma unroll
  for (int fm = 0; fm < 2; ++fm){
    #pragma unroll
    for (int fn = 0; fn < 2; ++fn){
      const f32x4 a = (fm==0) ? (fn==0 ? acc00 : acc01) : (fn==0 ? acc10 : acc11);
      int col = col0 + wc*32 + fn*16 + lr;
      float bv = bias ? bias[col] : 0.f;
      #pragma unroll
      for (int j = 0; j < 4; ++j){
        int row = row0 + wr*32 + fm*16 + lg*4 + j;
        if (row >= M) continue;
        float val = a[j] + bv;
        if (act) val = reluf(val);
        if constexpr (OBF == 0) ((float*)Cv)[(size_t)row*N + col] = val;
        else ((unsigned short*)Cv)[(size_t)row*N + col] = f2bf(val);
      }
    }
  }
}

// ================= fused policy tail: p2[N,64] -> relu(p2@W2+b2) @ w3 + b3 =================
__global__ __launch_bounds__(256) void policy_tail_kernel(
    const float* __restrict__ p2, const float* __restrict__ W2, const float* __restrict__ B2,
    const float* __restrict__ W3, const float* __restrict__ B3,
    float* __restrict__ out, int n){
  __shared__ float w2[64*32];
  __shared__ float w3[32];
  __shared__ float b2s[32];
  int t = threadIdx.x;
  for (int i = t; i < 2048; i += 256) w2[i] = W2[i];
  if (t < 32){ w3[t] = W3[t]; b2s[t] = B2[t]; }
  __syncthreads();
  int v = blockIdx.x*256 + t;
  if (v >= n) return;
  const float* row = p2 + (size_t)v*64;
  float acc32[32];
  #pragma unroll
  for (int o = 0; o < 32; ++o) acc32[o] = b2s[o];
  for (int k = 0; k < 64; ++k){
    float xk = row[k];
    #pragma unroll
    for (int o = 0; o < 32; ++o) acc32[o] += xk * w2[k*32 + o];
  }
  float accf = B3[0];
  #pragma unroll
  for (int o = 0; o < 32; ++o) accf += reluf(acc32[o]) * w3[o];
  out[v] = accf;
}

// ================= graph boundaries =================
__global__ void bounds_kernel(const int* __restrict__ batch, int* __restrict__ gstart,
                              int n, int G){
  int g = threadIdx.x;
  if (g > G) return;
  int lo = 0, hi = n;
  while (lo < hi){ int mid = (lo + hi) >> 1; if (batch[mid] < g) lo = mid + 1; else hi = mid; }
  gstart[g] = lo;
}

// ================= global add pool: 2-stage split reduction =================
__global__ __launch_bounds__(128) void pool_split_kernel(const float* __restrict__ x,
    const int* __restrict__ gstart, float* __restrict__ partial){
  int g = blockIdx.x, sp = blockIdx.y, f = threadIdx.x;
  int beg = gstart[g], end = gstart[g+1];
  int len = end - beg;
  int chunk = (len + POOL_SPLIT - 1) / POOL_SPLIT;
  int lo = beg + sp*chunk;
  int hi = min(lo + chunk, end);
  float acc = 0.f;
  for (int r = lo; r < hi; ++r) acc += x[(size_t)r*128 + f];
  partial[((size_t)g*POOL_SPLIT + sp)*128 + f] = acc;
}
__global__ __launch_bounds__(128) void pool_final_kernel(const float* __restrict__ partial,
    float* __restrict__ pooled){
  int g = blockIdx.x, f = threadIdx.x;
  float acc = 0.f;
  #pragma unroll
  for (int sp = 0; sp < POOL_SPLIT; ++sp)
    acc += partial[((size_t)g*POOL_SPLIT + sp)*128 + f];
  pooled[g*128 + f] = acc;
}

// ================= value MLP =================
__global__ __launch_bounds__(128) void value_mlp_kernel(const float* __restrict__ pooled,
    const float* __restrict__ W0, const float* __restrict__ B0,
    const float* __restrict__ W1, const float* __restrict__ B1,
    const float* __restrict__ W2, const float* __restrict__ B2,
    const float* __restrict__ W3, const float* __restrict__ B3,
    float* __restrict__ outv){
  __shared__ float a[128], b[128];
  int g = blockIdx.x, t = threadIdx.x;
  a[t] = pooled[g*128 + t];
  __syncthreads();
  float acc = B0[t];
  for (int k = 0; k < 128; ++k) acc += a[k]*W0[k*128 + t];
  b[t] = reluf(acc);
  __syncthreads();
  if (t < 64){ acc = B1[t]; for (int k = 0; k < 128; ++k) acc += b[k]*W1[k*64 + t]; a[t] = reluf(acc); }
  __syncthreads();
  if (t < 32){ acc = B2[t]; for (int k = 0; k < 64; ++k) acc += a[k]*W2[k*32 + t]; b[t] = reluf(acc); }
  __syncthreads();
  if (t == 0){ acc = B3[0]; for (int k = 0; k < 32; ++k) acc += b[k]*W3[k]; outv[g] = acc; }
}

extern "C" void kernel_launch(void* const* d_in, const int* in_sizes, int n_in,
                              void* d_out, int out_size, void* d_ws, size_t ws_size,
                              hipStream_t stream){
  const float* x     = (const float*)d_in[0];
  const int*   ei    = (const int*)d_in[1];
  const int*   batch = (const int*)d_in[2];
  const float* W1 = (const float*)d_in[3];
  const float* as1= (const float*)d_in[4];
  const float* ad1= (const float*)d_in[5];
  const float* b1 = (const float*)d_in[6];
  const float* W2 = (const float*)d_in[7];
  const float* as2= (const float*)d_in[8];
  const float* ad2= (const float*)d_in[9];
  const float* b2 = (const float*)d_in[10];
  const float* W3 = (const float*)d_in[11];
  const float* as3= (const float*)d_in[12];
  const float* ad3= (const float*)d_in[13];
  const float* b3 = (const float*)d_in[14];
  const float* pW0= (const float*)d_in[15];
  const float* pb0= (const float*)d_in[16];
  const float* pW1= (const float*)d_in[17];
  const float* pb1= (const float*)d_in[18];
  const float* pW2= (const float*)d_in[19];
  const float* pb2= (const float*)d_in[20];
  const float* pW3= (const float*)d_in[21];
  const float* pb3= (const float*)d_in[22];
  const float* vW0= (const float*)d_in[23];
  const float* vb0= (const float*)d_in[24];
  const float* vW1= (const float*)d_in[25];
  const float* vb1= (const float*)d_in[26];
  const float* vW2= (const float*)d_in[27];
  const float* vb2= (const float*)d_in[28];
  const float* vW3= (const float*)d_in[29];
  const float* vb3= (const float*)d_in[30];
  float* out = (float*)d_out;

  // -------- workspace carve --------
  char* ws = (char*)d_ws;
  size_t off = 0;
  auto carve = [&](size_t bytes)->char*{
    char* p = ws + off; off = (off + bytes + 255) & ~(size_t)255; return p;
  };
  int*   deg    = (int*)  carve((size_t)N_NODES*4);
  int*   rowptr = (int*)  carve((size_t)(N_NODES+1)*4);
  int*   pos    = (int*)  carve((size_t)N_EDGES*4);
  int*   csr    = (int*)  carve((size_t)N_EDGES*4);
  int*   bsum   = (int*)  carve(512*4);
  float* ew     = (float*)carve((size_t)N_EDGES*4);
  float* s      = (float*)carve((size_t)N_NODES*4);
  float* dsc    = (float*)carve((size_t)N_NODES*4);
  float* s2     = (float*)carve((size_t)N_NODES*4);
  float* d2     = (float*)carve((size_t)N_NODES*4);
  float* wa     = (float*)carve(1024*4);
  int*   gstart = (int*)  carve(65*4);
  float* pooled = (float*)carve((size_t)N_GRAPHS*128*4);
  float* partial= (float*)carve((size_t)N_GRAPHS*POOL_SPLIT*128*4);
  uint32_t*       xb   = (uint32_t*)      carve((size_t)N_NODES*64*2);   // bf16 [N,64] padded
  unsigned short* aggx = (unsigned short*)carve((size_t)N_NODES*64*2);   // bf16 [N,64]
  unsigned short* out1 = (unsigned short*)carve((size_t)N_NODES*256*2);  // bf16 [N,256]
  unsigned short* h2   = (unsigned short*)carve((size_t)N_NODES*128*2);  // bf16 [N,128]
  unsigned short* out2 = (unsigned short*)carve((size_t)N_NODES*128*2);  // bf16 [N,128]
  unsigned short* agg3 = (unsigned short*)carve((size_t)N_NODES*128*2);  // bf16 [N,128]
  float* out3 = (float*)carve((size_t)N_NODES*128*4);                    // f32 [N,128]
  // reuse dead regions for policy MLP intermediates
  unsigned short* p1 = h2;          // bf16 [N,128] — h2 dead after agg2
  float* p2 = (float*)out1;         // f32 [N,64] — out1 dead after gemm h2

  const int* esrc = ei;              // edge_index[0]
  const int* edst = ei + N_EDGES;    // edge_index[1]

  const int NBn  = (N_NODES + 255)/256;
  const int NBe  = (N_EDGES + 255)/256;
  const int GB   = (N_NODES + 63) / 64;   // 1563
  const int NB4  = (N_NODES + 3) / 4;
  const int NB8  = (N_NODES + 7) / 8;
  const int NB16 = (N_NODES + 15) / 16;

  // -------- prep: wa, CSR build, x->bf16+sd1, bounds --------
  wa_all_kernel<<<1, 256, 0, stream>>>(W1, as1, ad1, W2, as2, ad2, W3, as3, ad3, wa);
  zero_deg_kernel<<<NBn, 256, 0, stream>>>(deg, N_NODES);
  count_kernel<<<NBe, 256, 0, stream>>>(edst, deg, pos, N_EDGES);
  scan1_kernel<<<NBn, 256, 0, stream>>>(deg, rowptr, bsum, N_NODES);
  scan2_kernel<<<1, 512, 0, stream>>>(bsum, NBn);
  scan3_kernel<<<NBn, 256, 0, stream>>>(rowptr, bsum, N_NODES);
  scatter_kernel<<<NBe, 256, 0, stream>>>(esrc, edst, rowptr, pos, csr, N_EDGES);
  x2bf_sd_kernel<<<NB8, 256, 0, stream>>>(x, wa+0, wa+64, xb, s, dsc, N_NODES);
  bounds_kernel<<<1, 128, 0, stream>>>(batch, gstart, N_NODES, N_GRAPHS);

  // ---- layer 1 (pre-agg): agg(xb) -> GEMM(+b1,relu) -> out1 bf16
  agg_q<1,0,0><<<NB16, 256, 0, stream>>>((const unsigned short*)xb, s, dsc, rowptr, deg, csr, ew,
                                         nullptr, nullptr, nullptr, nullptr, nullptr,
                                         aggx, N_NODES);
  gemm_mfma<1,1><<<dim3(GB,4), 256, 0, stream>>>(aggx, W1, b1, out1, N_NODES, 64, 59, 256, 1);

  // ---- layer 2 (post-agg): sd(out1) -> GEMM -> h2 -> agg(+b2,relu, fused sd3->s2/d2) -> out2
  sd_bf16_kernel<<<NB4, 256, 0, stream>>>(out1, wa+128, wa+384, s, dsc, N_NODES, 256);
  gemm_mfma<1,1><<<dim3(GB,2), 256, 0, stream>>>(out1, W2, nullptr, h2, N_NODES, 256, 256, 128, 0);
  agg_q<2,1,1><<<NB16, 256, 0, stream>>>(h2, s, dsc, rowptr, deg, csr, ew,
                                         b2, wa+640, wa+768, s2, d2, out2, N_NODES);

  // ---- layer 3 (pre-agg): agg(out2, scores s2/d2) -> GEMM(+b3,relu) -> out3 f32
  agg_q<2,0,0><<<NB16, 256, 0, stream>>>(out2, s2, d2, rowptr, deg, csr, ew,
                                         nullptr, nullptr, nullptr, nullptr, nullptr,
                                         agg3, N_NODES);
  gemm_mfma<1,0><<<dim3(GB,2), 256, 0, stream>>>(agg3, W3, b3, out3, N_NODES, 128, 128, 128, 1);

  // ---- policy MLP: out3 -> p1(bf16) -> p2(f32) -> fused tail -> out[0..N)
  gemm_mfma<0,1><<<dim3(GB,2), 256, 0, stream>>>(out3, pW0, pb0, p1, N_NODES, 128, 128, 128, 1);
  gemm_mfma<1,0><<<dim3(GB,1), 256, 0, stream>>>(p1, pW1, pb1, p2, N_NODES, 128, 128, 64, 1);
  policy_tail_kernel<<<NBn, 256, 0, stream>>>(p2, pW2, pb2, pW3, pb3, out, N_NODES);

  // ---- pool + value MLP -> out[N..N+64)
  pool_split_kernel<<<dim3(N_GRAPHS, POOL_SPLIT), 128, 0, stream>>>(out3, gstart, partial);
  pool_final_kernel<<<N_GRAPHS, 128, 0, stream>>>(partial, pooled);
  value_mlp_kernel<<<N_GRAPHS, 128, 0, stream>>>(pooled, vW0, vb0, vW1, vb1, vW2, vb2, vW3, vb3,
                                                 out + N_NODES);
}

// Round 16
// 550.478 us; speedup vs baseline: 2.7260x; 1.0107x over previous
//
#include <hip/hip_runtime.h>
#include <hip/hip_bf16.h>
#include <cstdint>

#define N_NODES 100000
#define N_EDGES 800000
#define N_GRAPHS 64
#define POOL_SPLIT 16

typedef short short8 __attribute__((ext_vector_type(8)));
typedef float f32x4 __attribute__((ext_vector_type(4)));

__device__ __forceinline__ float leakyf(float x){ return x >= 0.0f ? x : 0.2f*x; }
__device__ __forceinline__ float reluf(float x){ return x > 0.0f ? x : 0.0f; }

__device__ __forceinline__ float bf2f(unsigned short u){
  union { uint32_t i; float f; } c; c.i = ((uint32_t)u) << 16; return c.f;
}
__device__ __forceinline__ unsigned short f2bf(float x){
  union { float f; uint32_t i; } c; c.f = x;
  uint32_t r = c.i + 0x7FFFu + ((c.i >> 16) & 1u);   // RNE
  return (unsigned short)(r >> 16);
}
__device__ __forceinline__ uint32_t pack2(float a, float b){
  return (uint32_t)f2bf(a) | ((uint32_t)f2bf(b) << 16);
}

// ================= CSR build =================
__global__ void zero_deg_kernel(int* __restrict__ deg, int n){
  int v = blockIdx.x*256 + threadIdx.x;
  if (v < n) deg[v] = 0;
}
__global__ void count_kernel(const int* __restrict__ dst, int* __restrict__ deg,
                             int* __restrict__ pos, int E){
  int e = blockIdx.x*256 + threadIdx.x;
  if (e < E) pos[e] = atomicAdd(&deg[dst[e]], 1);
}
__global__ __launch_bounds__(256) void scan1_kernel(const int* __restrict__ deg,
    int* __restrict__ rowptr, int* __restrict__ bsum, int n){
  __shared__ int sm[256];
  int t = threadIdx.x, i = blockIdx.x*256 + t;
  int v = (i < n) ? deg[i] : 0;
  sm[t] = v; __syncthreads();
  for (int off = 1; off < 256; off <<= 1){
    int x = (t >= off) ? sm[t-off] : 0;
    __syncthreads();
    sm[t] += x;
    __syncthreads();
  }
  if (i < n) rowptr[i] = sm[t] - v;
  if (t == 255) bsum[blockIdx.x] = sm[255];
}
__global__ __launch_bounds__(512) void scan2_kernel(int* __restrict__ bsum, int nb){
  __shared__ int sm[512];
  int t = threadIdx.x;
  int v = (t < nb) ? bsum[t] : 0;
  sm[t] = v; __syncthreads();
  for (int off = 1; off < 512; off <<= 1){
    int x = (t >= off) ? sm[t-off] : 0;
    __syncthreads();
    sm[t] += x;
    __syncthreads();
  }
  if (t < nb) bsum[t] = sm[t] - v;
}
__global__ void scan3_kernel(int* __restrict__ rowptr, const int* __restrict__ bsum, int n){
  int i = blockIdx.x*256 + threadIdx.x;
  if (i < n) rowptr[i] += bsum[blockIdx.x];
}
__global__ void scatter_kernel(const int* __restrict__ src, const int* __restrict__ dst,
                               const int* __restrict__ rowptr, const int* __restrict__ pos,
                               int* __restrict__ csr, int E){
  int e = blockIdx.x*256 + threadIdx.x;
  if (e < E) csr[rowptr[dst[e]] + pos[e]] = src[e];
}

// ================= all Wa = W @ a in one launch =================
// wa layout: [0:64) s1 | [64:128) d1 | [128:384) s2 | [384:640) d2 | [640:768) s3 | [768:896) d3
__global__ __launch_bounds__(256) void wa_all_kernel(
    const float* __restrict__ W1, const float* __restrict__ as1, const float* __restrict__ ad1,
    const float* __restrict__ W2, const float* __restrict__ as2, const float* __restrict__ ad2,
    const float* __restrict__ W3, const float* __restrict__ as3, const float* __restrict__ ad3,
    float* __restrict__ wa){
  int t = threadIdx.x;
  { float ss=0.f, dd=0.f; const float* wr = W2 + (size_t)t*128;
    for (int o=0;o<128;++o){ float w=wr[o]; ss+=w*as2[o]; dd+=w*ad2[o]; }
    wa[128+t]=ss; wa[384+t]=dd; }
  if (t < 128){ float ss=0.f, dd=0.f; const float* wr = W3 + (size_t)t*128;
    for (int o=0;o<128;++o){ float w=wr[o]; ss+=w*as3[o]; dd+=w*ad3[o]; }
    wa[640+t]=ss; wa[768+t]=dd; }
  if (t < 64){ float ss=0.f, dd=0.f;
    if (t < 59){ const float* wr = W1 + (size_t)t*256;
      for (int o=0;o<256;++o){ float w=wr[o]; ss+=w*as1[o]; dd+=w*ad1[o]; } }
    wa[t]=ss; wa[64+t]=dd; }
}

// ================= x -> bf16 [N,64] + layer-1 scores (fused) =================
// half-wave (32 lanes) per row: lane hl handles cols 2hl, 2hl+1
__global__ __launch_bounds__(256) void x2bf_sd_kernel(const float* __restrict__ x,
    const float* __restrict__ wa_s, const float* __restrict__ wa_d,
    uint32_t* __restrict__ xb, float* __restrict__ s, float* __restrict__ d, int n){
  int hl = threadIdx.x & 31;
  int v = blockIdx.x*8 + (threadIdx.x >> 5);
  if (v >= n) return;
  int c0 = 2*hl, c1 = 2*hl + 1;
  float f0 = (c0 < 59) ? x[(size_t)v*59 + c0] : 0.f;
  float f1 = (c1 < 59) ? x[(size_t)v*59 + c1] : 0.f;
  xb[(size_t)v*32 + hl] = pack2(f0, f1);
  float ss = f0*wa_s[c0] + f1*wa_s[c1];
  float dd = f0*wa_d[c0] + f1*wa_d[c1];
  #pragma unroll
  for (int off = 16; off; off >>= 1){ ss += __shfl_xor(ss, off); dd += __shfl_xor(dd, off); }
  if (hl == 0){ s[v] = ss; d[v] = dd; }
}

// ================= per-node scores (bf16 input, K even) =================
__global__ __launch_bounds__(256) void sd_bf16_kernel(const unsigned short* __restrict__ in,
    const float* __restrict__ wa_s, const float* __restrict__ wa_d,
    float* __restrict__ s, float* __restrict__ d, int n, int K){
  int wid = threadIdx.x >> 6, lane = threadIdx.x & 63;
  int v = (blockIdx.x << 2) + wid;
  if (v >= n) return;
  float ss = 0.f, dd = 0.f;
  const unsigned short* row = in + (size_t)v*K;
  for (int k = lane*2; k < K; k += 128){
    uint32_t u = *(const uint32_t*)&row[k];
    float x0 = bf2f((unsigned short)(u & 0xFFFFu));
    float x1 = bf2f((unsigned short)(u >> 16));
    ss += x0*wa_s[k] + x1*wa_s[k+1];
    dd += x0*wa_d[k] + x1*wa_d[k+1];
  }
  for (int off = 32; off; off >>= 1){ ss += __shfl_down(ss, off); dd += __shfl_down(dd, off); }
  if (lane == 0){ s[v] = ss; d[v] = dd; }
}

// ================= half-wave edge-softmax aggregation (bf16 in/out) =================
// NC=1: C=64 cols, lane loads uint (2 ch). NC=2: C=128 cols, lane loads uint2 (4 ch).
template<int NC>
__device__ __forceinline__ void gload(const unsigned short* rowp, int hl, float* f){
  if constexpr (NC == 1){
    uint32_t u = ((const uint32_t*)rowp)[hl];
    f[0] = bf2f((unsigned short)(u & 0xFFFFu));
    f[1] = bf2f((unsigned short)(u >> 16));
  } else {
    uint2 u = ((const uint2*)rowp)[hl];
    f[0] = bf2f((unsigned short)(u.x & 0xFFFFu));
    f[1] = bf2f((unsigned short)(u.x >> 16));
    f[2] = bf2f((unsigned short)(u.y & 0xFFFFu));
    f[3] = bf2f((unsigned short)(u.y >> 16));
  }
}

// BR: bias+relu epilogue. SDF: fuse next-layer score computation.
// 8 nodes per 256-thread block; each half-wave (32 lanes) owns one dst node.
// Proven config (round 11: 43.6 us for NC=2); quarter-wave regressed (round 15: 48.8).
template<int NC, int BR, int SDF>
__global__ __launch_bounds__(256) void agg_half(
    const unsigned short* __restrict__ hb, const float* __restrict__ s,
    const float* __restrict__ dsc, const int* __restrict__ rowptr,
    const int* __restrict__ deg, const int* __restrict__ csr, float* __restrict__ ew,
    const float* __restrict__ bias,
    const float* __restrict__ sdw_s, const float* __restrict__ sdw_d,
    float* __restrict__ s_out, float* __restrict__ d_out,
    unsigned short* __restrict__ outp, int n){
  const int C  = NC*64;
  const int CH = NC*2;                    // channels per lane
  const int tid  = threadIdx.x;
  const int hl   = tid & 31;
  const int base = tid & 32;              // half-wave base lane within wave
  const int v = blockIdx.x*8 + (tid >> 5);
  if (v >= n) return;
  const int beg = rowptr[v], dg = deg[v];
  const float dv = dsc[v];
  const float e0 = leakyf(s[v] + dv);
  float acc[CH];

  if (dg <= 32){
    int srcl = 0; float sc = -1e30f;
    if (hl < dg){ srcl = csr[beg + hl]; sc = leakyf(s[srcl] + dv); }
    float mm = sc;
    #pragma unroll
    for (int off = 16; off; off >>= 1) mm = fmaxf(mm, __shfl_xor(mm, off));
    const float m = fmaxf(e0, mm);
    float w = (hl < dg) ? __expf(sc - m) : 0.f;
    float den = w;
    #pragma unroll
    for (int off = 16; off; off >>= 1) den += __shfl_xor(den, off);
    const float ws0 = __expf(e0 - m);
    const float inv = 1.0f / (den + ws0 + 1e-16f);
    const float wl = w * inv;
    {
      float f[CH]; gload<NC>(hb + (size_t)v*C, hl, f);
      const float w0 = ws0 * inv;
      #pragma unroll
      for (int c = 0; c < CH; ++c) acc[c] = w0 * f[c];
    }
    int j = 0;
    for (; j + 4 <= dg; j += 4){
      int  s0 = __shfl(srcl, base+j),   s1 = __shfl(srcl, base+j+1);
      int  s2 = __shfl(srcl, base+j+2), s3 = __shfl(srcl, base+j+3);
      float w0_ = __shfl(wl, base+j),   w1_ = __shfl(wl, base+j+1);
      float w2_ = __shfl(wl, base+j+2), w3_ = __shfl(wl, base+j+3);
      float f0[CH], f1[CH], f2[CH], f3[CH];
      gload<NC>(hb + (size_t)s0*C, hl, f0);
      gload<NC>(hb + (size_t)s1*C, hl, f1);
      gload<NC>(hb + (size_t)s2*C, hl, f2);
      gload<NC>(hb + (size_t)s3*C, hl, f3);
      #pragma unroll
      for (int c = 0; c < CH; ++c)
        acc[c] += w0_*f0[c] + w1_*f1[c] + w2_*f2[c] + w3_*f3[c];
    }
    for (; j < dg; ++j){
      int src = __shfl(srcl, base+j);
      float w_ = __shfl(wl, base+j);
      float f[CH]; gload<NC>(hb + (size_t)src*C, hl, f);
      #pragma unroll
      for (int c = 0; c < CH; ++c) acc[c] += w_*f[c];
    }
  } else {
    // chunked path (dg>32, rare): spill scores to ew
    float m = e0;
    for (int b0 = 0; b0 < dg; b0 += 32){
      int i = b0 + hl; float sc = -1e30f;
      if (i < dg){ int src = csr[beg + i]; sc = leakyf(s[src] + dv); ew[beg + i] = sc; }
      #pragma unroll
      for (int off = 16; off; off >>= 1) sc = fmaxf(sc, __shfl_xor(sc, off));
      m = fmaxf(m, sc);
    }
    float dsum = 0.f;
    for (int b0 = 0; b0 < dg; b0 += 32){
      int i = b0 + hl; float w = 0.f;
      if (i < dg){ w = __expf(ew[beg + i] - m); ew[beg + i] = w; }
      float cs = w;
      #pragma unroll
      for (int off = 16; off; off >>= 1) cs += __shfl_xor(cs, off);
      dsum += cs;
    }
    const float ws0 = __expf(e0 - m);
    const float inv = 1.0f / (dsum + ws0 + 1e-16f);
    {
      float f[CH]; gload<NC>(hb + (size_t)v*C, hl, f);
      const float w0 = ws0 * inv;
      #pragma unroll
      for (int c = 0; c < CH; ++c) acc[c] = w0 * f[c];
    }
    for (int b0 = 0; b0 < dg; b0 += 32){
      int i = b0 + hl;
      int srcl = 0; float wl = 0.f;
      if (i < dg){ srcl = csr[beg + i]; wl = ew[beg + i] * inv; }
      int cnt = min(32, dg - b0);
      for (int j = 0; j < cnt; ++j){
        int src = __shfl(srcl, base+j);
        float w_ = __shfl(wl, base+j);
        float f[CH]; gload<NC>(hb + (size_t)src*C, hl, f);
        #pragma unroll
        for (int c = 0; c < CH; ++c) acc[c] += w_*f[c];
      }
    }
  }

  // epilogue: bias+relu (BR), pack+store, fused next-layer scores (SDF)
  float vout[CH];
  #pragma unroll
  for (int c = 0; c < CH; ++c){
    float val = acc[c];
    if constexpr (BR) val = reluf(val + bias[CH*hl + c]);
    vout[c] = val;
  }
  unsigned short* op = outp + (size_t)v*C;
  if constexpr (NC == 1){
    ((uint32_t*)op)[hl] = pack2(vout[0], vout[1]);
  } else {
    uint2 u; u.x = pack2(vout[0], vout[1]); u.y = pack2(vout[2], vout[3]);
    ((uint2*)op)[hl] = u;
  }
  if constexpr (SDF){
    float ss = 0.f, dd = 0.f;
    #pragma unroll
    for (int c = 0; c < CH; ++c){
      ss += vout[c] * sdw_s[CH*hl + c];
      dd += vout[c] * sdw_d[CH*hl + c];
    }
    #pragma unroll
    for (int off = 16; off; off >>= 1){ ss += __shfl_xor(ss, off); dd += __shfl_xor(dd, off); }
    if (hl == 0){ s_out[v] = ss; d_out[v] = dd; }
  }
}

// ================= MFMA bf16 GEMM: C = A[MxK] @ W[KxN] (+bias)(+relu) =================
// 64x64 tile, BK=32, 4 waves 2x2. N%64==0. A f32 (ABF=0) or bf16 (ABF=1).
// W f32 [Kw x N]; rows gk>=Kw read as 0 (A zero-padded there).
template<int ABF, int OBF>
__global__ __launch_bounds__(256) void gemm_mfma(
    const void* __restrict__ Av, const float* __restrict__ W,
    const float* __restrict__ bias, void* __restrict__ Cv,
    int M, int K, int Kw, int N, int act){
  __shared__ short As[64][40];
  __shared__ short Bs[64][40];
  const int t = threadIdx.x;
  const int row0 = blockIdx.x * 64;
  const int col0 = blockIdx.y * 64;
  const int wv = t >> 6, lane = t & 63;
  const int wr = wv >> 1, wc = wv & 1;
  const int lr = lane & 15, lg = lane >> 4;

  f32x4 acc00 = {}, acc01 = {}, acc10 = {}, acc11 = {};

  for (int k0 = 0; k0 < K; k0 += 32){
    {
      int m = t >> 2, kq = (t & 3) * 8;
      int gr = row0 + m;
      short8 av;
      if constexpr (ABF == 1){
        const unsigned short* Au = (const unsigned short*)Av;
        if (gr < M && (k0 + kq + 7) < K){
          av = *(const short8*)&Au[(size_t)gr*K + k0 + kq];
        } else {
          #pragma unroll
          for (int j = 0; j < 8; ++j){
            int gk = k0 + kq + j;
            av[j] = (gr < M && gk < K) ? (short)Au[(size_t)gr*K + gk] : (short)0;
          }
        }
      } else {
        const float* Af = (const float*)Av;
        if (gr < M && (K % 4) == 0 && (k0 + kq + 7) < K){
          const float4 f0 = *(const float4*)&Af[(size_t)gr*K + k0 + kq];
          const float4 f1 = *(const float4*)&Af[(size_t)gr*K + k0 + kq + 4];
          av[0]=f2bf(f0.x); av[1]=f2bf(f0.y); av[2]=f2bf(f0.z); av[3]=f2bf(f0.w);
          av[4]=f2bf(f1.x); av[5]=f2bf(f1.y); av[6]=f2bf(f1.z); av[7]=f2bf(f1.w);
        } else {
          #pragma unroll
          for (int j = 0; j < 8; ++j){
            int gk = k0 + kq + j;
            float val = (gr < M && gk < K) ? Af[(size_t)gr*K + gk] : 0.f;
            av[j] = f2bf(val);
          }
        }
      }
      *(short8*)&As[m][kq] = av;
    }
    {
      int n = t & 63, k8 = (t >> 6) * 8;
      short8 bv;
      #pragma unroll
      for (int j = 0; j < 8; ++j){
        int gk = k0 + k8 + j;
        float val = (gk < Kw) ? W[(size_t)gk*N + col0 + n] : 0.f;
        bv[j] = f2bf(val);
      }
      *(short8*)&Bs[n][k8] = bv;
    }
    __syncthreads();
    short8 af0 = *(short8*)&As[wr*32 +  0 + lr][lg*8];
    short8 af1 = *(short8*)&As[wr*32 + 16 + lr][lg*8];
    short8 bf0 = *(short8*)&Bs[wc*32 +  0 + lr][lg*8];
    short8 bf1 = *(short8*)&Bs[wc*32 + 16 + lr][lg*8];
    acc00 = __builtin_amdgcn_mfma_f32_16x16x32_bf16(af0, bf0, acc00, 0, 0, 0);
    acc01 = __builtin_amdgcn_mfma_f32_16x16x32_bf16(af0, bf1, acc01, 0, 0, 0);
    acc10 = __builtin_amdgcn_mfma_f32_16x16x32_bf16(af1, bf0, acc10, 0, 0, 0);
    acc11 = __builtin_amdgcn_mfma_f32_16x16x32_bf16(af1, bf1, acc11, 0, 0, 0);
    __syncthreads();
  }

  #pragma unroll
  for (int fm = 0; fm < 2; ++fm){
    #pragma unroll
    for (int fn = 0; fn < 2; ++fn){
      const f32x4 a = (fm==0) ? (fn==0 ? acc00 : acc01) : (fn==0 ? acc10 : acc11);
      int col = col0 + wc*32 + fn*16 + lr;
      float bv = bias ? bias[col] : 0.f;
      #pragma unroll
      for (int j = 0; j < 4; ++j){
        int row = row0 + wr*32 + fm*16 + lg*4 + j;
        if (row >= M) continue;
        float val = a[j] + bv;
        if (act) val = reluf(val);
        if constexpr (OBF == 0) ((float*)Cv)[(size_t)row*N + col] = val;
        else ((unsigned short*)Cv)[(size_t)row*N + col] = f2bf(val);
      }
    }
  }
}

// ================= fused policy tail: p2[N,64] -> relu(p2@W2+b2) @ w3 + b3 =================
__global__ __launch_bounds__(256) void policy_tail_kernel(
    const float* __restrict__ p2, const float* __restrict__ W2, const float* __restrict__ B2,
    const float* __restrict__ W3, const float* __restrict__ B3,
    float* __restrict__ out, int n){
  __shared__ float w2[64*32];
  __shared__ float w3[32];
  __shared__ float b2s[32];
  int t = threadIdx.x;
  for (int i = t; i < 2048; i += 256) w2[i] = W2[i];
  if (t < 32){ w3[t] = W3[t]; b2s[t] = B2[t]; }
  __syncthreads();
  int v = blockIdx.x*256 + t;
  if (v >= n) return;
  const float* row = p2 + (size_t)v*64;
  float acc32[32];
  #pragma unroll
  for (int o = 0; o < 32; ++o) acc32[o] = b2s[o];
  for (int k = 0; k < 64; ++k){
    float xk = row[k];
    #pragma unroll
    for (int o = 0; o < 32; ++o) acc32[o] += xk * w2[k*32 + o];
  }
  float accf = B3[0];
  #pragma unroll
  for (int o = 0; o < 32; ++o) accf += reluf(acc32[o]) * w3[o];
  out[v] = accf;
}

// ================= graph boundaries =================
__global__ void bounds_kernel(const int* __restrict__ batch, int* __restrict__ gstart,
                              int n, int G){
  int g = threadIdx.x;
  if (g > G) return;
  int lo = 0, hi = n;
  while (lo < hi){ int mid = (lo + hi) >> 1; if (batch[mid] < g) lo = mid + 1; else hi = mid; }
  gstart[g] = lo;
}

// ================= global add pool: 2-stage split reduction =================
__global__ __launch_bounds__(128) void pool_split_kernel(const float* __restrict__ x,
    const int* __restrict__ gstart, float* __restrict__ partial){
  int g = blockIdx.x, sp = blockIdx.y, f = threadIdx.x;
  int beg = gstart[g], end = gstart[g+1];
  int len = end - beg;
  int chunk = (len + POOL_SPLIT - 1) / POOL_SPLIT;
  int lo = beg + sp*chunk;
  int hi = min(lo + chunk, end);
  float acc = 0.f;
  for (int r = lo; r < hi; ++r) acc += x[(size_t)r*128 + f];
  partial[((size_t)g*POOL_SPLIT + sp)*128 + f] = acc;
}
__global__ __launch_bounds__(128) void pool_final_kernel(const float* __restrict__ partial,
    float* __restrict__ pooled){
  int g = blockIdx.x, f = threadIdx.x;
  float acc = 0.f;
  #pragma unroll
  for (int sp = 0; sp < POOL_SPLIT; ++sp)
    acc += partial[((size_t)g*POOL_SPLIT + sp)*128 + f];
  pooled[g*128 + f] = acc;
}

// ================= value MLP =================
__global__ __launch_bounds__(128) void value_mlp_kernel(const float* __restrict__ pooled,
    const float* __restrict__ W0, const float* __restrict__ B0,
    const float* __restrict__ W1, const float* __restrict__ B1,
    const float* __restrict__ W2, const float* __restrict__ B2,
    const float* __restrict__ W3, const float* __restrict__ B3,
    float* __restrict__ outv){
  __shared__ float a[128], b[128];
  int g = blockIdx.x, t = threadIdx.x;
  a[t] = pooled[g*128 + t];
  __syncthreads();
  float acc = B0[t];
  for (int k = 0; k < 128; ++k) acc += a[k]*W0[k*128 + t];
  b[t] = reluf(acc);
  __syncthreads();
  if (t < 64){ acc = B1[t]; for (int k = 0; k < 128; ++k) acc += b[k]*W1[k*64 + t]; a[t] = reluf(acc); }
  __syncthreads();
  if (t < 32){ acc = B2[t]; for (int k = 0; k < 64; ++k) acc += a[k]*W2[k*32 + t]; b[t] = reluf(acc); }
  __syncthreads();
  if (t == 0){ acc = B3[0]; for (int k = 0; k < 32; ++k) acc += b[k]*W3[k]; outv[g] = acc; }
}

extern "C" void kernel_launch(void* const* d_in, const int* in_sizes, int n_in,
                              void* d_out, int out_size, void* d_ws, size_t ws_size,
                              hipStream_t stream){
  const float* x     = (const float*)d_in[0];
  const int*   ei    = (const int*)d_in[1];
  const int*   batch = (const int*)d_in[2];
  const float* W1 = (const float*)d_in[3];
  const float* as1= (const float*)d_in[4];
  const float* ad1= (const float*)d_in[5];
  const float* b1 = (const float*)d_in[6];
  const float* W2 = (const float*)d_in[7];
  const float* as2= (const float*)d_in[8];
  const float* ad2= (const float*)d_in[9];
  const float* b2 = (const float*)d_in[10];
  const float* W3 = (const float*)d_in[11];
  const float* as3= (const float*)d_in[12];
  const float* ad3= (const float*)d_in[13];
  const float* b3 = (const float*)d_in[14];
  const float* pW0= (const float*)d_in[15];
  const float* pb0= (const float*)d_in[16];
  const float* pW1= (const float*)d_in[17];
  const float* pb1= (const float*)d_in[18];
  const float* pW2= (const float*)d_in[19];
  const float* pb2= (const float*)d_in[20];
  const float* pW3= (const float*)d_in[21];
  const float* pb3= (const float*)d_in[22];
  const float* vW0= (const float*)d_in[23];
  const float* vb0= (const float*)d_in[24];
  const float* vW1= (const float*)d_in[25];
  const float* vb1= (const float*)d_in[26];
  const float* vW2= (const float*)d_in[27];
  const float* vb2= (const float*)d_in[28];
  const float* vW3= (const float*)d_in[29];
  const float* vb3= (const float*)d_in[30];
  float* out = (float*)d_out;

  // -------- workspace carve --------
  char* ws = (char*)d_ws;
  size_t off = 0;
  auto carve = [&](size_t bytes)->char*{
    char* p = ws + off; off = (off + bytes + 255) & ~(size_t)255; return p;
  };
  int*   deg    = (int*)  carve((size_t)N_NODES*4);
  int*   rowptr = (int*)  carve((size_t)(N_NODES+1)*4);
  int*   pos    = (int*)  carve((size_t)N_EDGES*4);
  int*   csr    = (int*)  carve((size_t)N_EDGES*4);
  int*   bsum   = (int*)  carve(512*4);
  float* ew     = (float*)carve((size_t)N_EDGES*4);
  float* s      = (float*)carve((size_t)N_NODES*4);
  float* dsc    = (float*)carve((size_t)N_NODES*4);
  float* s2     = (float*)carve((size_t)N_NODES*4);
  float* d2     = (float*)carve((size_t)N_NODES*4);
  float* wa     = (float*)carve(1024*4);
  int*   gstart = (int*)  carve(65*4);
  float* pooled = (float*)carve((size_t)N_GRAPHS*128*4);
  float* partial= (float*)carve((size_t)N_GRAPHS*POOL_SPLIT*128*4);
  uint32_t*       xb   = (uint32_t*)      carve((size_t)N_NODES*64*2);   // bf16 [N,64] padded
  unsigned short* aggx = (unsigned short*)carve((size_t)N_NODES*64*2);   // bf16 [N,64]
  unsigned short* out1 = (unsigned short*)carve((size_t)N_NODES*256*2);  // bf16 [N,256]
  unsigned short* h2   = (unsigned short*)carve((size_t)N_NODES*128*2);  // bf16 [N,128]
  unsigned short* out2 = (unsigned short*)carve((size_t)N_NODES*128*2);  // bf16 [N,128]
  unsigned short* agg3 = (unsigned short*)carve((size_t)N_NODES*128*2);  // bf16 [N,128]
  float* out3 = (float*)carve((size_t)N_NODES*128*4);                    // f32 [N,128]
  // reuse dead regions for policy MLP intermediates
  unsigned short* p1 = h2;          // bf16 [N,128] — h2 dead after agg2
  float* p2 = (float*)out1;         // f32 [N,64] — out1 dead after gemm h2

  const int* esrc = ei;              // edge_index[0]
  const int* edst = ei + N_EDGES;    // edge_index[1]

  const int NBn  = (N_NODES + 255)/256;
  const int NBe  = (N_EDGES + 255)/256;
  const int GB   = (N_NODES + 63) / 64;   // 1563
  const int NB4  = (N_NODES + 3) / 4;
  const int NB8  = (N_NODES + 7) / 8;

  // -------- prep: wa, CSR build, x->bf16+sd1, bounds --------
  wa_all_kernel<<<1, 256, 0, stream>>>(W1, as1, ad1, W2, as2, ad2, W3, as3, ad3, wa);
  zero_deg_kernel<<<NBn, 256, 0, stream>>>(deg, N_NODES);
  count_kernel<<<NBe, 256, 0, stream>>>(edst, deg, pos, N_EDGES);
  scan1_kernel<<<NBn, 256, 0, stream>>>(deg, rowptr, bsum, N_NODES);
  scan2_kernel<<<1, 512, 0, stream>>>(bsum, NBn);
  scan3_kernel<<<NBn, 256, 0, stream>>>(rowptr, bsum, N_NODES);
  scatter_kernel<<<NBe, 256, 0, stream>>>(esrc, edst, rowptr, pos, csr, N_EDGES);
  x2bf_sd_kernel<<<NB8, 256, 0, stream>>>(x, wa+0, wa+64, xb, s, dsc, N_NODES);
  bounds_kernel<<<1, 128, 0, stream>>>(batch, gstart, N_NODES, N_GRAPHS);

  // ---- layer 1 (pre-agg): agg(xb) -> GEMM(+b1,relu) -> out1 bf16
  agg_half<1,0,0><<<NB8, 256, 0, stream>>>((const unsigned short*)xb, s, dsc, rowptr, deg, csr, ew,
                                           nullptr, nullptr, nullptr, nullptr, nullptr,
                                           aggx, N_NODES);
  gemm_mfma<1,1><<<dim3(GB,4), 256, 0, stream>>>(aggx, W1, b1, out1, N_NODES, 64, 59, 256, 1);

  // ---- layer 2 (post-agg): sd(out1) -> GEMM -> h2 -> agg(+b2,relu, fused sd3->s2/d2) -> out2
  sd_bf16_kernel<<<NB4, 256, 0, stream>>>(out1, wa+128, wa+384, s, dsc, N_NODES, 256);
  gemm_mfma<1,1><<<dim3(GB,2), 256, 0, stream>>>(out1, W2, nullptr, h2, N_NODES, 256, 256, 128, 0);
  agg_half<2,1,1><<<NB8, 256, 0, stream>>>(h2, s, dsc, rowptr, deg, csr, ew,
                                           b2, wa+640, wa+768, s2, d2, out2, N_NODES);

  // ---- layer 3 (pre-agg): agg(out2, scores s2/d2) -> GEMM(+b3,relu) -> out3 f32
  agg_half<2,0,0><<<NB8, 256, 0, stream>>>(out2, s2, d2, rowptr, deg, csr, ew,
                                           nullptr, nullptr, nullptr, nullptr, nullptr,
                                           agg3, N_NODES);
  gemm_mfma<1,0><<<dim3(GB,2), 256, 0, stream>>>(agg3, W3, b3, out3, N_NODES, 128, 128, 128, 1);

  // ---- policy MLP: out3 -> p1(bf16) -> p2(f32) -> fused tail -> out[0..N)
  gemm_mfma<0,1><<<dim3(GB,2), 256, 0, stream>>>(out3, pW0, pb0, p1, N_NODES, 128, 128, 128, 1);
  gemm_mfma<1,0><<<dim3(GB,1), 256, 0, stream>>>(p1, pW1, pb1, p2, N_NODES, 128, 128, 64, 1);
  policy_tail_kernel<<<NBn, 256, 0, stream>>>(p2, pW2, pb2, pW3, pb3, out, N_NODES);

  // ---- pool + value MLP -> out[N..N+64)
  pool_split_kernel<<<dim3(N_GRAPHS, POOL_SPLIT), 128, 0, stream>>>(out3, gstart, partial);
  pool_final_kernel<<<N_GRAPHS, 128, 0, stream>>>(partial, pooled);
  value_mlp_kernel<<<N_GRAPHS, 128, 0, stream>>>(pooled, vW0, vb0, vW1, vb1, vW2, vb2, vW3, vb3,
                                                 out + N_NODES);
}